// Round 6
// baseline (453.633 us; speedup 1.0000x reference)
//
#include <hip/hip_runtime.h>
#include <math.h>

#define CDIM 512
#define NDIM 4096
#define KDIM 64
#define BDIM 16
#define NSPLIT 8

typedef __attribute__((ext_vector_type(8))) _Float16 f16x8;
typedef __attribute__((ext_vector_type(4))) _Float16 f16x4;
typedef __attribute__((ext_vector_type(4))) float f32x4;

__device__ __forceinline__ void g2lds16(const void* g, void* l) {
  __builtin_amdgcn_global_load_lds(
      (const __attribute__((address_space(1))) int*)g,
      (__attribute__((address_space(3))) int*)l, 16, 0, 0);
}

__device__ __forceinline__ f16x8 ldsfrag(const short* base, int row, int kk,
                                         int lh) {
  int slot = (kk * 4 + lh) ^ (row & 7);
  return *reinterpret_cast<const f16x8*>(&base[row * 64 + slot * 8]);
}

// ---------------------------------------------------------------------------
// x [b][c][n] f32 -> xT [b][n][c] fp16.  grid (N/64, C/64, B)
// ---------------------------------------------------------------------------
__global__ __launch_bounds__(256) void k_cvtT16(const float* __restrict__ in,
                                                _Float16* __restrict__ outT) {
  __shared__ __align__(16) _Float16 T[64][80];
  const int t = threadIdx.x;
  const int n0 = blockIdx.x * 64, c0 = blockIdx.y * 64;
  const float* ib = in + (size_t)blockIdx.z * CDIM * NDIM;
  _Float16* ob = outT + (size_t)blockIdx.z * NDIM * CDIM;
#pragma unroll
  for (int i = 0; i < 4; ++i) {
    int idx = i * 256 + t;
    int cl = idx >> 4, f4 = idx & 15;
    float4 v = *reinterpret_cast<const float4*>(
        &ib[(size_t)(c0 + cl) * NDIM + n0 + f4 * 4]);
    T[f4 * 4 + 0][cl] = (_Float16)v.x;
    T[f4 * 4 + 1][cl] = (_Float16)v.y;
    T[f4 * 4 + 2][cl] = (_Float16)v.z;
    T[f4 * 4 + 3][cl] = (_Float16)v.w;
  }
  __syncthreads();
#pragma unroll
  for (int i = 0; i < 2; ++i) {
    int idx = i * 256 + t;
    int nl = idx >> 3, ch = idx & 7;
    uint4 u = *reinterpret_cast<const uint4*>(&T[nl][ch * 8]);
    *reinterpret_cast<uint4*>(&ob[(size_t)(n0 + nl) * CDIM + c0 + ch * 8]) = u;
  }
}

// ---------------------------------------------------------------------------
// weights f32 -> fp16
// ---------------------------------------------------------------------------
__global__ void k_cvt_w16(const float* __restrict__ w,
                          _Float16* __restrict__ wh) {
  int i = (blockIdx.x * 256 + threadIdx.x) * 4;
  float4 v = *reinterpret_cast<const float4*>(&w[i]);
  wh[i] = (_Float16)v.x; wh[i + 1] = (_Float16)v.y;
  wh[i + 2] = (_Float16)v.z; wh[i + 3] = (_Float16)v.w;
}

// ---------------------------------------------------------------------------
// conv1: xf = W1*x + b1, dual-layout output:
//   xfT[b][n][o] fp16 (scalar writes) and xf[b][o][n] fp16 (via LDS transpose)
// grid (N/128, C/128, B); 128x128 tile, BK=64, 4 waves.
// ---------------------------------------------------------------------------
__global__ __launch_bounds__(256) void k_conv1_16(
    const _Float16* __restrict__ xT, const _Float16* __restrict__ w1,
    const float* __restrict__ b1, _Float16* __restrict__ xfT,
    _Float16* __restrict__ xf) {
  __shared__ __align__(16) short smem[17408];  // At[8192] Bt[8192]; Ot overlays
  short* At = smem;
  short* Bt = smem + 8192;
  const int tid = threadIdx.x;
  const int l = tid & 63, w = tid >> 6;
  const int wm = w >> 1, wn = w & 1;
  const int lr = l & 15, lh = l >> 4;
  const int i0 = blockIdx.x * 128;  // n
  const int j0 = blockIdx.y * 128;  // o
  const int b = blockIdx.z;
  const short* Ag = (const short*)(xT + (size_t)b * NDIM * CDIM);
  const short* Bg = (const short*)w1;
  f32x4 acc[4][4] = {};
  for (int c0 = 0; c0 < CDIM; c0 += 64) {
#pragma unroll
    for (int i = 0; i < 4; ++i) {
      int slot = i * 256 + tid;
      int r = slot >> 3, s = slot & 7, sp = s ^ (r & 7);
      g2lds16(Ag + (size_t)(i0 + r) * CDIM + c0 + sp * 8, At + slot * 8);
    }
#pragma unroll
    for (int i = 0; i < 4; ++i) {
      int slot = i * 256 + tid;
      int r = slot >> 3, s = slot & 7, sp = s ^ (r & 7);
      g2lds16(Bg + (size_t)(j0 + r) * CDIM + c0 + sp * 8, Bt + slot * 8);
    }
    __syncthreads();
#pragma unroll
    for (int kk = 0; kk < 2; ++kk) {
      f16x8 af[4], bf[4];
#pragma unroll
      for (int m = 0; m < 4; ++m) af[m] = ldsfrag(At, wm * 64 + m * 16 + lr, kk, lh);
#pragma unroll
      for (int nf = 0; nf < 4; ++nf) bf[nf] = ldsfrag(Bt, wn * 64 + nf * 16 + lr, kk, lh);
#pragma unroll
      for (int m = 0; m < 4; ++m)
#pragma unroll
        for (int nf = 0; nf < 4; ++nf)
          acc[m][nf] = __builtin_amdgcn_mfma_f32_16x16x32_f16(af[m], bf[nf],
                                                              acc[m][nf], 0, 0, 0);
    }
    __syncthreads();
  }
  // Epilogue: xfT scalar writes + scatter into Ot[o][n] (pad 136)
  _Float16* Otf = (_Float16*)smem;
  _Float16* ob = xfT + (size_t)b * NDIM * CDIM;
#pragma unroll
  for (int m = 0; m < 4; ++m) {
#pragma unroll
    for (int nf = 0; nf < 4; ++nf) {
      int ol = wn * 64 + nf * 16 + lr;
      float bv = b1[j0 + ol];
#pragma unroll
      for (int r = 0; r < 4; ++r) {
        int nl = wm * 64 + m * 16 + lh * 4 + r;
        _Float16 hv = (_Float16)(acc[m][nf][r] + bv);
        ob[(size_t)(i0 + nl) * CDIM + j0 + ol] = hv;
        Otf[ol * 136 + nl] = hv;
      }
    }
  }
  __syncthreads();
  _Float16* xfb = xf + (size_t)b * CDIM * NDIM;
#pragma unroll
  for (int i = 0; i < 8; ++i) {
    int seg = i * 256 + tid;
    int row = seg >> 4, cs = seg & 15;
    f16x8 v = *reinterpret_cast<const f16x8*>(&Otf[row * 136 + cs * 8]);
    *reinterpret_cast<f16x8*>(&xfb[(size_t)(j0 + row) * NDIM + i0 + cs * 8]) = v;
  }
}

// ---------------------------------------------------------------------------
// init muT[b][k][c] fp16 = mu[c][k]
// ---------------------------------------------------------------------------
__global__ void k_init_mu16(const float* __restrict__ mu,
                            _Float16* __restrict__ muT) {
  int idx = blockIdx.x * 256 + threadIdx.x;  // 524288
  int rem = idx & 32767;
  int k = rem >> 9, c = rem & 511;
  muT[idx] = (_Float16)mu[c * KDIM + k];
}

// ---------------------------------------------------------------------------
// S1 (fp16 MFMA): logits[n][k] = sum_c xfT[n][c] muT[k][c]; z=softmax_k;
// writes z[b][n][k], zT[b][k][n] fp16, colsum[b][k] f32 atomics.
// grid (N/128, B). 128n x 64k tile; 4 waves own 32 n-rows each.
// ---------------------------------------------------------------------------
__global__ __launch_bounds__(256) void k_s1_16(const _Float16* __restrict__ xfT,
                                               const _Float16* __restrict__ muT,
                                               _Float16* __restrict__ z,
                                               _Float16* __restrict__ zT,
                                               float* __restrict__ colsum) {
  __shared__ __align__(16) short At[128 * 64];
  __shared__ __align__(16) short Bt[64 * 64];
  __shared__ __align__(16) _Float16 zs[128][72];
  __shared__ float csum[4][64];
  const int tid = threadIdx.x;
  const int l = tid & 63, w = tid >> 6;
  const int lr = l & 15, lh = l >> 4;
  const int n0 = blockIdx.x * 128;
  const int b = blockIdx.y;
  const short* Ag = (const short*)(xfT + (size_t)b * NDIM * CDIM);
  const short* Bg = (const short*)(muT + (size_t)b * KDIM * CDIM);
  f32x4 acc[2][4] = {};
  for (int c0 = 0; c0 < CDIM; c0 += 64) {
#pragma unroll
    for (int i = 0; i < 4; ++i) {
      int slot = i * 256 + tid;
      int r = slot >> 3, s = slot & 7, sp = s ^ (r & 7);
      g2lds16(Ag + (size_t)(n0 + r) * CDIM + c0 + sp * 8, At + slot * 8);
    }
#pragma unroll
    for (int i = 0; i < 2; ++i) {
      int slot = i * 256 + tid;
      int r = slot >> 3, s = slot & 7, sp = s ^ (r & 7);
      g2lds16(Bg + (size_t)r * CDIM + c0 + sp * 8, Bt + slot * 8);
    }
    __syncthreads();
#pragma unroll
    for (int kk = 0; kk < 2; ++kk) {
      f16x8 af[2], bf;
#pragma unroll
      for (int nf = 0; nf < 2; ++nf)
        af[nf] = ldsfrag(At, w * 32 + nf * 16 + lr, kk, lh);
#pragma unroll
      for (int kf = 0; kf < 4; ++kf) {
        bf = ldsfrag(Bt, kf * 16 + lr, kk, lh);
#pragma unroll
        for (int nf = 0; nf < 2; ++nf)
          acc[nf][kf] = __builtin_amdgcn_mfma_f32_16x16x32_f16(af[nf], bf,
                                                               acc[nf][kf], 0, 0, 0);
      }
    }
    __syncthreads();
  }
#pragma unroll
  for (int nf = 0; nf < 2; ++nf) {
#pragma unroll
    for (int r = 0; r < 4; ++r) {
      float m = fmaxf(fmaxf(acc[nf][0][r], acc[nf][1][r]),
                      fmaxf(acc[nf][2][r], acc[nf][3][r]));
#pragma unroll
      for (int d = 8; d >= 1; d >>= 1) m = fmaxf(m, __shfl_xor(m, d));
      float e[4], s = 0.f;
#pragma unroll
      for (int kf = 0; kf < 4; ++kf) { e[kf] = __expf(acc[nf][kf][r] - m); s += e[kf]; }
#pragma unroll
      for (int d = 8; d >= 1; d >>= 1) s += __shfl_xor(s, d);
      float inv = 1.f / s;
      int row = w * 32 + nf * 16 + lh * 4 + r;
#pragma unroll
      for (int kf = 0; kf < 4; ++kf)
        zs[row][kf * 16 + lr] = (_Float16)(e[kf] * inv);
    }
  }
  __syncthreads();
  _Float16* zb = z + (size_t)b * NDIM * KDIM;
  _Float16* zTb = zT + (size_t)b * KDIM * NDIM;
#pragma unroll
  for (int i = 0; i < 4; ++i) {  // z[n][k]
    int idx = i * 256 + tid;
    int n = idx >> 3, ch = idx & 7;
    *reinterpret_cast<uint4*>(&zb[(size_t)(n0 + n) * KDIM + ch * 8]) =
        *reinterpret_cast<const uint4*>(&zs[n][ch * 8]);
  }
#pragma unroll
  for (int i = 0; i < 4; ++i) {  // zT[k][n]
    int idx = i * 256 + tid;
    int k = idx >> 4, nch = idx & 15;
    f16x8 v;
#pragma unroll
    for (int j = 0; j < 8; ++j) v[j] = zs[nch * 8 + j][k];
    *reinterpret_cast<f16x8*>(&zTb[(size_t)k * NDIM + n0 + nch * 8]) = v;
  }
  {  // colsum: thread (q=tid>>6, k=tid&63) sums 32 rows
    int k = tid & 63, q = tid >> 6;
    float s = 0.f;
#pragma unroll
    for (int n = 0; n < 32; ++n) s += (float)zs[q * 32 + n][k];
    csum[q][k] = s;
  }
  __syncthreads();
  if (tid < 64)
    atomicAdd(&colsum[b * KDIM + tid],
              csum[0][tid] + csum[1][tid] + csum[2][tid] + csum[3][tid]);
}

// ---------------------------------------------------------------------------
// S2 (fp16 MFMA): mupart[b][k][c] += sum_{n in split} zT[k][n] xf[c][n]
// (device atomicAdd accumulation across splits)  grid (C/128, NSPLIT, B)
// ---------------------------------------------------------------------------
__global__ __launch_bounds__(256) void k_s2_16(const _Float16* __restrict__ zT,
                                               const _Float16* __restrict__ xf,
                                               float* __restrict__ mupart) {
  __shared__ __align__(16) short At[64 * 64];
  __shared__ __align__(16) short Bt[128 * 64];
  const int tid = threadIdx.x;
  const int l = tid & 63, w = tid >> 6;
  const int lr = l & 15, lh = l >> 4;
  const int c0 = blockIdx.x * 128;
  const int split = blockIdx.y;
  const int b = blockIdx.z;
  const short* Ag = (const short*)(zT + (size_t)b * KDIM * NDIM);
  const short* Bg = (const short*)(xf + (size_t)b * CDIM * NDIM);
  f32x4 acc[4][2] = {};
  for (int st = 0; st < 8; ++st) {
    const int nb = split * (NDIM / NSPLIT) + st * 64;
#pragma unroll
    for (int i = 0; i < 2; ++i) {
      int slot = i * 256 + tid;
      int r = slot >> 3, s = slot & 7, sp = s ^ (r & 7);
      g2lds16(Ag + (size_t)r * NDIM + nb + sp * 8, At + slot * 8);
    }
#pragma unroll
    for (int i = 0; i < 4; ++i) {
      int slot = i * 256 + tid;
      int r = slot >> 3, s = slot & 7, sp = s ^ (r & 7);
      g2lds16(Bg + (size_t)(c0 + r) * NDIM + nb + sp * 8, Bt + slot * 8);
    }
    __syncthreads();
#pragma unroll
    for (int kk = 0; kk < 2; ++kk) {
      f16x8 bf[2], af;
#pragma unroll
      for (int cf = 0; cf < 2; ++cf)
        bf[cf] = ldsfrag(Bt, w * 32 + cf * 16 + lr, kk, lh);
#pragma unroll
      for (int kf = 0; kf < 4; ++kf) {
        af = ldsfrag(At, kf * 16 + lr, kk, lh);
#pragma unroll
        for (int cf = 0; cf < 2; ++cf)
          acc[kf][cf] = __builtin_amdgcn_mfma_f32_16x16x32_f16(af, bf[cf],
                                                               acc[kf][cf], 0, 0, 0);
      }
    }
    __syncthreads();
  }
  float* mp = mupart + (size_t)b * KDIM * CDIM;
#pragma unroll
  for (int kf = 0; kf < 4; ++kf) {
    int k = kf * 16 + lh * 4;
#pragma unroll
    for (int r = 0; r < 4; ++r)
#pragma unroll
      for (int cf = 0; cf < 2; ++cf)
        atomicAdd(&mp[(size_t)(k + r) * CDIM + c0 + w * 32 + cf * 16 + lr],
                  acc[kf][cf][r]);
  }
}

// ---------------------------------------------------------------------------
// S2 reduce: t = mupart[b][k][:]*scs[k]; out = t/(1e-6+|t|_2)
// ---------------------------------------------------------------------------
__global__ __launch_bounds__(256) void k_s2red(const float* __restrict__ mupart,
                                               const float* __restrict__ colsum,
                                               _Float16* __restrict__ muT,
                                               _Float16* __restrict__ mu_ck) {
  __shared__ float red[4];
  const int tid = threadIdx.x;
  const int b = blockIdx.x >> 6, k = blockIdx.x & 63;
  const float* mp = mupart + ((size_t)b * KDIM + k) * CDIM;
  float v0 = mp[tid];
  float v1 = mp[tid + 256];
  float ssq = v0 * v0 + v1 * v1;
#pragma unroll
  for (int d = 32; d >= 1; d >>= 1) ssq += __shfl_down(ssq, d);
  if ((tid & 63) == 0) red[tid >> 6] = ssq;
  __syncthreads();
  float tot = red[0] + red[1] + red[2] + red[3];
  float scs = 1.f / (1e-6f + colsum[b * KDIM + k]);
  float inv = scs / (1e-6f + scs * sqrtf(tot));
  _Float16 o0 = (_Float16)(v0 * inv), o1 = (_Float16)(v1 * inv);
  muT[((size_t)b * KDIM + k) * CDIM + tid] = o0;
  muT[((size_t)b * KDIM + k) * CDIM + tid + 256] = o1;
  mu_ck[((size_t)b * CDIM + tid) * KDIM + k] = o0;
  mu_ck[((size_t)b * CDIM + tid + 256) * KDIM + k] = o1;
}

// ---------------------------------------------------------------------------
// Fused recon+conv2: per block (n-tile 128, batch b):
//  phase1: R[n][c] = relu(sum_k z[n][k] mu_ck[c][k]) into 128KB LDS (swizzled)
//  phase2: y16[o][n] = sum_c w2[o][c] R[n][c]; fused BN partial stats.
// 512 threads (8 waves), grid (N/128, B). mu/w2 read from global (L2-resident).
// ---------------------------------------------------------------------------
__global__ __launch_bounds__(512, 2) void k_rc2(
    const _Float16* __restrict__ z, const _Float16* __restrict__ mu_ck,
    const _Float16* __restrict__ w2, _Float16* __restrict__ y16,
    float* __restrict__ bnsum, float* __restrict__ bnsumsq) {
  __shared__ __align__(16) short R[128 * 512];  // 128 KB
  _Float16* Rh = (_Float16*)R;
  const int tid = threadIdx.x;
  const int l = tid & 63, w = tid >> 6;  // 8 waves
  const int lr = l & 15, lh = (l >> 4) & 3;
  const int n0 = blockIdx.x * 128;
  const int b = blockIdx.y;

  // ---- phase 1: wave w computes R rows [w*16, w*16+16) ----
  const short* zg = (const short*)(z + (size_t)b * NDIM * KDIM);
  const short* mg = (const short*)(mu_ck + (size_t)b * CDIM * KDIM);
  f16x8 zf[2];
  {
    const short* zrow = zg + (size_t)(n0 + w * 16 + lr) * KDIM;
#pragma unroll
    for (int kk = 0; kk < 2; ++kk)
      zf[kk] = *reinterpret_cast<const f16x8*>(zrow + kk * 32 + lh * 8);
  }
#pragma unroll
  for (int cc = 0; cc < 4; ++cc) {  // 128-c chunks
    f32x4 acc[8] = {};
#pragma unroll
    for (int kk = 0; kk < 2; ++kk) {
#pragma unroll
      for (int cf = 0; cf < 8; ++cf) {
        const short* mrow = mg + (size_t)(cc * 128 + cf * 16 + lr) * KDIM;
        f16x8 bf = *reinterpret_cast<const f16x8*>(mrow + kk * 32 + lh * 8);
        acc[cf] = __builtin_amdgcn_mfma_f32_16x16x32_f16(zf[kk], bf, acc[cf],
                                                         0, 0, 0);
      }
    }
#pragma unroll
    for (int cf = 0; cf < 8; ++cf) {
#pragma unroll
      for (int r = 0; r < 4; ++r) {
        int n = w * 16 + lh * 4 + r;
        int c = cc * 128 + cf * 16 + lr;
        Rh[n * 512 + ((c >> 3) ^ (n & 7)) * 8 + (c & 7)] =
            (_Float16)fmaxf(acc[cf][r], 0.f);
      }
    }
  }
  __syncthreads();

  // ---- phase 2: wave w computes y rows [w*64, w*64+64) for all 128 n ----
  const short* wg = (const short*)w2;
  _Float16* yb = y16 + (size_t)b * CDIM * NDIM;
  f32x4 acc2[4][8] = {};
  for (int cs = 0; cs < 8; ++cs) {  // 64-c steps
#pragma unroll
    for (int kk = 0; kk < 2; ++kk) {
      f16x8 af[4], bf[8];
#pragma unroll
      for (int mf = 0; mf < 4; ++mf) {
        const short* wrow = wg + (size_t)(w * 64 + mf * 16 + lr) * CDIM;
        af[mf] = *reinterpret_cast<const f16x8*>(wrow + cs * 64 + kk * 32 + lh * 8);
      }
#pragma unroll
      for (int nf = 0; nf < 8; ++nf) {
        int n = nf * 16 + lr;
        int slot = (cs * 8 + kk * 4 + lh) ^ (n & 7);
        bf[nf] = *reinterpret_cast<const f16x8*>(&R[n * 512 + slot * 8]);
      }
#pragma unroll
      for (int mf = 0; mf < 4; ++mf)
#pragma unroll
        for (int nf = 0; nf < 8; ++nf)
          acc2[mf][nf] = __builtin_amdgcn_mfma_f32_16x16x32_f16(
              af[mf], bf[nf], acc2[mf][nf], 0, 0, 0);
    }
  }
#pragma unroll
  for (int mf = 0; mf < 4; ++mf) {
#pragma unroll
    for (int r = 0; r < 4; ++r) {
      int o = w * 64 + mf * 16 + lh * 4 + r;
      float ps = 0.f, pq = 0.f;
#pragma unroll
      for (int nf = 0; nf < 8; ++nf) {
        float v = acc2[mf][nf][r];
        ps += v; pq += v * v;
        yb[(size_t)o * NDIM + n0 + nf * 16 + lr] = (_Float16)v;
      }
#pragma unroll
      for (int d = 1; d < 16; d <<= 1) {
        ps += __shfl_xor(ps, d);
        pq += __shfl_xor(pq, d);
      }
      if (lr == 0) {
        atomicAdd(&bnsum[o], ps);
        atomicAdd(&bnsumsq[o], pq);
      }
    }
  }
}

// ---------------------------------------------------------------------------
// final: out = relu((y-mean)*rsqrt(var+eps)*gamma + beta + x), y fp16
// ---------------------------------------------------------------------------
__global__ void k_final(float* __restrict__ out, const _Float16* __restrict__ y16,
                        const float* __restrict__ x,
                        const float* __restrict__ bnsum,
                        const float* __restrict__ bnsumsq,
                        const float* __restrict__ gamma,
                        const float* __restrict__ beta) {
  const float invM = 1.f / (BDIM * (float)NDIM);
  const size_t total4 = (size_t)BDIM * CDIM * NDIM / 4;
  for (size_t i4 = (size_t)blockIdx.x * 256 + threadIdx.x; i4 < total4;
       i4 += (size_t)gridDim.x * 256) {
    int c = (int)((i4 >> 10) & (CDIM - 1));
    float mean = bnsum[c] * invM;
    float var = bnsumsq[c] * invM - mean * mean;
    float sc = rsqrtf(var + 1e-5f) * gamma[c];
    float sh = beta[c] - mean * sc;
    f16x4 yv = *reinterpret_cast<const f16x4*>(&y16[i4 * 4]);
    float4 xv = reinterpret_cast<const float4*>(x)[i4];
    float4 o;
    o.x = fmaxf(fmaf((float)yv[0], sc, sh) + xv.x, 0.f);
    o.y = fmaxf(fmaf((float)yv[1], sc, sh) + xv.y, 0.f);
    o.z = fmaxf(fmaf((float)yv[2], sc, sh) + xv.z, 0.f);
    o.w = fmaxf(fmaf((float)yv[3], sc, sh) + xv.w, 0.f);
    reinterpret_cast<float4*>(out)[i4] = o;
  }
}

// ---------------------------------------------------------------------------
extern "C" void kernel_launch(void* const* d_in, const int* in_sizes, int n_in,
                              void* d_out, int out_size, void* d_ws,
                              size_t ws_size, hipStream_t stream) {
  const float* x = (const float*)d_in[0];
  const float* mu = (const float*)d_in[1];
  const float* w1 = (const float*)d_in[2];
  const float* b1 = (const float*)d_in[3];
  const float* w2 = (const float*)d_in[4];
  const float* gamma = (const float*)d_in[5];
  const float* beta = (const float*)d_in[6];
  float* out = (float*)d_out;

  // xf dual copies live in d_out until k_final overwrites it.
  _Float16* xfT = (_Float16*)d_out;              // [B][N][C]
  _Float16* xf = (_Float16*)d_out + 33554432;    // [B][C][N]

  _Float16* wsH = (_Float16*)d_ws;
  _Float16* xT = wsH;                            // [B][N][C]
  _Float16* z = wsH + 33554432;                  // [B][N][K]
  _Float16* zT = z + 4194304;                    // [B][K][N]
  _Float16* muT = zT + 4194304;                  // [B][K][C]
  _Float16* mu_ck = muT + 524288;                // [B][C][K]
  _Float16* w1h = mu_ck + 524288;                // [C][C]
  _Float16* w2h = w1h + 262144;
  float* wsF = (float*)(w2h + 262144);
  float* mupart = wsF;                           // [B][K][C] f32 (2 MB)
  float* colsum = mupart + 524288;               // [B][K]
  float* bnsum = colsum + 1024;                  // [C]
  float* bnsumsq = bnsum + 512;                  // [C]
  _Float16* y16 = (_Float16*)(bnsumsq + 512);    // [B][C][N] fp16

  k_cvtT16<<<dim3(NDIM / 64, CDIM / 64, BDIM), 256, 0, stream>>>(x, xT);
  k_cvt_w16<<<CDIM * CDIM / 1024, 256, 0, stream>>>(w1, w1h);
  k_cvt_w16<<<CDIM * CDIM / 1024, 256, 0, stream>>>(w2, w2h);

  k_conv1_16<<<dim3(NDIM / 128, CDIM / 128, BDIM), 256, 0, stream>>>(
      xT, w1h, b1, xfT, xf);
  k_init_mu16<<<2048, 256, 0, stream>>>(mu, muT);

  for (int s = 0; s < 3; ++s) {
    hipMemsetAsync(colsum, 0, 1024 * sizeof(float), stream);
    k_s1_16<<<dim3(NDIM / 128, BDIM), 256, 0, stream>>>(xfT, muT, z, zT, colsum);
    hipMemsetAsync(mupart, 0, 524288 * sizeof(float), stream);
    k_s2_16<<<dim3(CDIM / 128, NSPLIT, BDIM), 256, 0, stream>>>(zT, xf, mupart);
    k_s2red<<<KDIM * BDIM, 256, 0, stream>>>(mupart, colsum, muT, mu_ck);
  }

  hipMemsetAsync(bnsum, 0, 1024 * sizeof(float), stream);
  k_rc2<<<dim3(NDIM / 128, BDIM), 512, 0, stream>>>(z, mu_ck, w2h, y16, bnsum,
                                                    bnsumsq);

  k_final<<<4096, 256, 0, stream>>>(out, y16, x, bnsum, bnsumsq, gamma, beta);
}

// Round 7
// 453.492 us; speedup vs baseline: 1.0003x; 1.0003x over previous
//
#include <hip/hip_runtime.h>
#include <math.h>

#define CDIM 512
#define NDIM 4096
#define KDIM 64
#define BDIM 16
#define NSPLIT 8

typedef __attribute__((ext_vector_type(8))) _Float16 f16x8;
typedef __attribute__((ext_vector_type(4))) _Float16 f16x4;
typedef __attribute__((ext_vector_type(4))) float f32x4;

__device__ __forceinline__ void g2lds16(const void* g, void* l) {
  __builtin_amdgcn_global_load_lds(
      (const __attribute__((address_space(1))) int*)g,
      (__attribute__((address_space(3))) int*)l, 16, 0, 0);
}

__device__ __forceinline__ f16x8 ldsfrag(const short* base, int row, int kk,
                                         int lh) {
  int slot = (kk * 4 + lh) ^ (row & 7);
  return *reinterpret_cast<const f16x8*>(&base[row * 64 + slot * 8]);
}

// ---------------------------------------------------------------------------
// x [b][c][n] f32 -> xT [b][n][c] fp16.  grid (N/64, C/64, B)
// ---------------------------------------------------------------------------
__global__ __launch_bounds__(256) void k_cvtT16(const float* __restrict__ in,
                                                _Float16* __restrict__ outT) {
  __shared__ __align__(16) _Float16 T[64][80];
  const int t = threadIdx.x;
  const int n0 = blockIdx.x * 64, c0 = blockIdx.y * 64;
  const float* ib = in + (size_t)blockIdx.z * CDIM * NDIM;
  _Float16* ob = outT + (size_t)blockIdx.z * NDIM * CDIM;
#pragma unroll
  for (int i = 0; i < 4; ++i) {
    int idx = i * 256 + t;
    int cl = idx >> 4, f4 = idx & 15;
    float4 v = *reinterpret_cast<const float4*>(
        &ib[(size_t)(c0 + cl) * NDIM + n0 + f4 * 4]);
    T[f4 * 4 + 0][cl] = (_Float16)v.x;
    T[f4 * 4 + 1][cl] = (_Float16)v.y;
    T[f4 * 4 + 2][cl] = (_Float16)v.z;
    T[f4 * 4 + 3][cl] = (_Float16)v.w;
  }
  __syncthreads();
#pragma unroll
  for (int i = 0; i < 2; ++i) {
    int idx = i * 256 + t;
    int nl = idx >> 3, ch = idx & 7;
    uint4 u = *reinterpret_cast<const uint4*>(&T[nl][ch * 8]);
    *reinterpret_cast<uint4*>(&ob[(size_t)(n0 + nl) * CDIM + c0 + ch * 8]) = u;
  }
}

// ---------------------------------------------------------------------------
// weights f32 -> fp16
// ---------------------------------------------------------------------------
__global__ void k_cvt_w16(const float* __restrict__ w,
                          _Float16* __restrict__ wh) {
  int i = (blockIdx.x * 256 + threadIdx.x) * 4;
  float4 v = *reinterpret_cast<const float4*>(&w[i]);
  wh[i] = (_Float16)v.x; wh[i + 1] = (_Float16)v.y;
  wh[i + 2] = (_Float16)v.z; wh[i + 3] = (_Float16)v.w;
}

// ---------------------------------------------------------------------------
// conv1: xf = W1*x + b1, dual-layout output:
//   xfT[b][n][o] fp16 (scalar writes) and xf[b][o][n] fp16 (via LDS transpose)
// grid (N/128, C/128, B); 128x128 tile, BK=64, 4 waves.
// ---------------------------------------------------------------------------
__global__ __launch_bounds__(256) void k_conv1_16(
    const _Float16* __restrict__ xT, const _Float16* __restrict__ w1,
    const float* __restrict__ b1, _Float16* __restrict__ xfT,
    _Float16* __restrict__ xf) {
  __shared__ __align__(16) short smem[17408];  // At[8192] Bt[8192]; Ot overlays
  short* At = smem;
  short* Bt = smem + 8192;
  const int tid = threadIdx.x;
  const int l = tid & 63, w = tid >> 6;
  const int wm = w >> 1, wn = w & 1;
  const int lr = l & 15, lh = l >> 4;
  const int i0 = blockIdx.x * 128;  // n
  const int j0 = blockIdx.y * 128;  // o
  const int b = blockIdx.z;
  const short* Ag = (const short*)(xT + (size_t)b * NDIM * CDIM);
  const short* Bg = (const short*)w1;
  f32x4 acc[4][4] = {};
  for (int c0 = 0; c0 < CDIM; c0 += 64) {
#pragma unroll
    for (int i = 0; i < 4; ++i) {
      int slot = i * 256 + tid;
      int r = slot >> 3, s = slot & 7, sp = s ^ (r & 7);
      g2lds16(Ag + (size_t)(i0 + r) * CDIM + c0 + sp * 8, At + slot * 8);
    }
#pragma unroll
    for (int i = 0; i < 4; ++i) {
      int slot = i * 256 + tid;
      int r = slot >> 3, s = slot & 7, sp = s ^ (r & 7);
      g2lds16(Bg + (size_t)(j0 + r) * CDIM + c0 + sp * 8, Bt + slot * 8);
    }
    __syncthreads();
#pragma unroll
    for (int kk = 0; kk < 2; ++kk) {
      f16x8 af[4], bf[4];
#pragma unroll
      for (int m = 0; m < 4; ++m) af[m] = ldsfrag(At, wm * 64 + m * 16 + lr, kk, lh);
#pragma unroll
      for (int nf = 0; nf < 4; ++nf) bf[nf] = ldsfrag(Bt, wn * 64 + nf * 16 + lr, kk, lh);
#pragma unroll
      for (int m = 0; m < 4; ++m)
#pragma unroll
        for (int nf = 0; nf < 4; ++nf)
          acc[m][nf] = __builtin_amdgcn_mfma_f32_16x16x32_f16(af[m], bf[nf],
                                                              acc[m][nf], 0, 0, 0);
    }
    __syncthreads();
  }
  // Epilogue: xfT scalar writes + scatter into Ot[o][n] (pad 136)
  _Float16* Otf = (_Float16*)smem;
  _Float16* ob = xfT + (size_t)b * NDIM * CDIM;
#pragma unroll
  for (int m = 0; m < 4; ++m) {
#pragma unroll
    for (int nf = 0; nf < 4; ++nf) {
      int ol = wn * 64 + nf * 16 + lr;
      float bv = b1[j0 + ol];
#pragma unroll
      for (int r = 0; r < 4; ++r) {
        int nl = wm * 64 + m * 16 + lh * 4 + r;
        _Float16 hv = (_Float16)(acc[m][nf][r] + bv);
        ob[(size_t)(i0 + nl) * CDIM + j0 + ol] = hv;
        Otf[ol * 136 + nl] = hv;
      }
    }
  }
  __syncthreads();
  _Float16* xfb = xf + (size_t)b * CDIM * NDIM;
#pragma unroll
  for (int i = 0; i < 8; ++i) {
    int seg = i * 256 + tid;
    int row = seg >> 4, cs = seg & 15;
    f16x8 v = *reinterpret_cast<const f16x8*>(&Otf[row * 136 + cs * 8]);
    *reinterpret_cast<f16x8*>(&xfb[(size_t)(j0 + row) * NDIM + i0 + cs * 8]) = v;
  }
}

// ---------------------------------------------------------------------------
// init muT[b][k][c] fp16 = mu[c][k]
// ---------------------------------------------------------------------------
__global__ void k_init_mu16(const float* __restrict__ mu,
                            _Float16* __restrict__ muT) {
  int idx = blockIdx.x * 256 + threadIdx.x;  // 524288
  int rem = idx & 32767;
  int k = rem >> 9, c = rem & 511;
  muT[idx] = (_Float16)mu[c * KDIM + k];
}

// ---------------------------------------------------------------------------
// S1 (fp16 MFMA): logits[n][k] = sum_c xfT[n][c] muT[k][c]; z=softmax_k;
// writes z[b][n][k], zT[b][k][n] fp16, colsum[b][k] f32 atomics.
// grid (N/128, B). 128n x 64k tile; 4 waves own 32 n-rows each.
// ---------------------------------------------------------------------------
__global__ __launch_bounds__(256) void k_s1_16(const _Float16* __restrict__ xfT,
                                               const _Float16* __restrict__ muT,
                                               _Float16* __restrict__ z,
                                               _Float16* __restrict__ zT,
                                               float* __restrict__ colsum) {
  __shared__ __align__(16) short At[128 * 64];
  __shared__ __align__(16) short Bt[64 * 64];
  __shared__ __align__(16) _Float16 zs[128][72];
  __shared__ float csum[4][64];
  const int tid = threadIdx.x;
  const int l = tid & 63, w = tid >> 6;
  const int lr = l & 15, lh = l >> 4;
  const int n0 = blockIdx.x * 128;
  const int b = blockIdx.y;
  const short* Ag = (const short*)(xfT + (size_t)b * NDIM * CDIM);
  const short* Bg = (const short*)(muT + (size_t)b * KDIM * CDIM);
  f32x4 acc[2][4] = {};
  for (int c0 = 0; c0 < CDIM; c0 += 64) {
#pragma unroll
    for (int i = 0; i < 4; ++i) {
      int slot = i * 256 + tid;
      int r = slot >> 3, s = slot & 7, sp = s ^ (r & 7);
      g2lds16(Ag + (size_t)(n0 + r) * CDIM + c0 + sp * 8, At + slot * 8);
    }
#pragma unroll
    for (int i = 0; i < 2; ++i) {
      int slot = i * 256 + tid;
      int r = slot >> 3, s = slot & 7, sp = s ^ (r & 7);
      g2lds16(Bg + (size_t)r * CDIM + c0 + sp * 8, Bt + slot * 8);
    }
    __syncthreads();
#pragma unroll
    for (int kk = 0; kk < 2; ++kk) {
      f16x8 af[2], bf;
#pragma unroll
      for (int nf = 0; nf < 2; ++nf)
        af[nf] = ldsfrag(At, w * 32 + nf * 16 + lr, kk, lh);
#pragma unroll
      for (int kf = 0; kf < 4; ++kf) {
        bf = ldsfrag(Bt, kf * 16 + lr, kk, lh);
#pragma unroll
        for (int nf = 0; nf < 2; ++nf)
          acc[nf][kf] = __builtin_amdgcn_mfma_f32_16x16x32_f16(af[nf], bf,
                                                               acc[nf][kf], 0, 0, 0);
      }
    }
    __syncthreads();
  }
#pragma unroll
  for (int nf = 0; nf < 2; ++nf) {
#pragma unroll
    for (int r = 0; r < 4; ++r) {
      float m = fmaxf(fmaxf(acc[nf][0][r], acc[nf][1][r]),
                      fmaxf(acc[nf][2][r], acc[nf][3][r]));
#pragma unroll
      for (int d = 8; d >= 1; d >>= 1) m = fmaxf(m, __shfl_xor(m, d));
      float e[4], s = 0.f;
#pragma unroll
      for (int kf = 0; kf < 4; ++kf) { e[kf] = __expf(acc[nf][kf][r] - m); s += e[kf]; }
#pragma unroll
      for (int d = 8; d >= 1; d >>= 1) s += __shfl_xor(s, d);
      float inv = 1.f / s;
      int row = w * 32 + nf * 16 + lh * 4 + r;
#pragma unroll
      for (int kf = 0; kf < 4; ++kf)
        zs[row][kf * 16 + lr] = (_Float16)(e[kf] * inv);
    }
  }
  __syncthreads();
  _Float16* zb = z + (size_t)b * NDIM * KDIM;
  _Float16* zTb = zT + (size_t)b * KDIM * NDIM;
#pragma unroll
  for (int i = 0; i < 4; ++i) {  // z[n][k]
    int idx = i * 256 + tid;
    int n = idx >> 3, ch = idx & 7;
    *reinterpret_cast<uint4*>(&zb[(size_t)(n0 + n) * KDIM + ch * 8]) =
        *reinterpret_cast<const uint4*>(&zs[n][ch * 8]);
  }
#pragma unroll
  for (int i = 0; i < 4; ++i) {  // zT[k][n]
    int idx = i * 256 + tid;
    int k = idx >> 4, nch = idx & 15;
    f16x8 v;
#pragma unroll
    for (int j = 0; j < 8; ++j) v[j] = zs[nch * 8 + j][k];
    *reinterpret_cast<f16x8*>(&zTb[(size_t)k * NDIM + n0 + nch * 8]) = v;
  }
  {  // colsum: thread (q=tid>>6, k=tid&63) sums 32 rows
    int k = tid & 63, q = tid >> 6;
    float s = 0.f;
#pragma unroll
    for (int n = 0; n < 32; ++n) s += (float)zs[q * 32 + n][k];
    csum[q][k] = s;
  }
  __syncthreads();
  if (tid < 64)
    atomicAdd(&colsum[b * KDIM + tid],
              csum[0][tid] + csum[1][tid] + csum[2][tid] + csum[3][tid]);
}

// ---------------------------------------------------------------------------
// S2 (fp16 MFMA): mupart[b][k][c] += sum_{n in split} zT[k][n] xf[c][n]
// (device atomicAdd accumulation across splits)  grid (C/128, NSPLIT, B)
// ---------------------------------------------------------------------------
__global__ __launch_bounds__(256) void k_s2_16(const _Float16* __restrict__ zT,
                                               const _Float16* __restrict__ xf,
                                               float* __restrict__ mupart) {
  __shared__ __align__(16) short At[64 * 64];
  __shared__ __align__(16) short Bt[128 * 64];
  const int tid = threadIdx.x;
  const int l = tid & 63, w = tid >> 6;
  const int lr = l & 15, lh = l >> 4;
  const int c0 = blockIdx.x * 128;
  const int split = blockIdx.y;
  const int b = blockIdx.z;
  const short* Ag = (const short*)(zT + (size_t)b * KDIM * NDIM);
  const short* Bg = (const short*)(xf + (size_t)b * CDIM * NDIM);
  f32x4 acc[4][2] = {};
  for (int st = 0; st < 8; ++st) {
    const int nb = split * (NDIM / NSPLIT) + st * 64;
#pragma unroll
    for (int i = 0; i < 2; ++i) {
      int slot = i * 256 + tid;
      int r = slot >> 3, s = slot & 7, sp = s ^ (r & 7);
      g2lds16(Ag + (size_t)r * NDIM + nb + sp * 8, At + slot * 8);
    }
#pragma unroll
    for (int i = 0; i < 4; ++i) {
      int slot = i * 256 + tid;
      int r = slot >> 3, s = slot & 7, sp = s ^ (r & 7);
      g2lds16(Bg + (size_t)(c0 + r) * NDIM + nb + sp * 8, Bt + slot * 8);
    }
    __syncthreads();
#pragma unroll
    for (int kk = 0; kk < 2; ++kk) {
      f16x8 bf[2], af;
#pragma unroll
      for (int cf = 0; cf < 2; ++cf)
        bf[cf] = ldsfrag(Bt, w * 32 + cf * 16 + lr, kk, lh);
#pragma unroll
      for (int kf = 0; kf < 4; ++kf) {
        af = ldsfrag(At, kf * 16 + lr, kk, lh);
#pragma unroll
        for (int cf = 0; cf < 2; ++cf)
          acc[kf][cf] = __builtin_amdgcn_mfma_f32_16x16x32_f16(af, bf[cf],
                                                               acc[kf][cf], 0, 0, 0);
      }
    }
    __syncthreads();
  }
  float* mp = mupart + (size_t)b * KDIM * CDIM;
#pragma unroll
  for (int kf = 0; kf < 4; ++kf) {
    int k = kf * 16 + lh * 4;
#pragma unroll
    for (int r = 0; r < 4; ++r)
#pragma unroll
      for (int cf = 0; cf < 2; ++cf)
        atomicAdd(&mp[(size_t)(k + r) * CDIM + c0 + w * 32 + cf * 16 + lr],
                  acc[kf][cf][r]);
  }
}

// ---------------------------------------------------------------------------
// S2 reduce: t = mupart[b][k][:]*scs[k]; out = t/(1e-6+|t|_2)
// ---------------------------------------------------------------------------
__global__ __launch_bounds__(256) void k_s2red(const float* __restrict__ mupart,
                                               const float* __restrict__ colsum,
                                               _Float16* __restrict__ muT,
                                               _Float16* __restrict__ mu_ck) {
  __shared__ float red[4];
  const int tid = threadIdx.x;
  const int b = blockIdx.x >> 6, k = blockIdx.x & 63;
  const float* mp = mupart + ((size_t)b * KDIM + k) * CDIM;
  float v0 = mp[tid];
  float v1 = mp[tid + 256];
  float ssq = v0 * v0 + v1 * v1;
#pragma unroll
  for (int d = 32; d >= 1; d >>= 1) ssq += __shfl_down(ssq, d);
  if ((tid & 63) == 0) red[tid >> 6] = ssq;
  __syncthreads();
  float tot = red[0] + red[1] + red[2] + red[3];
  float scs = 1.f / (1e-6f + colsum[b * KDIM + k]);
  float inv = scs / (1e-6f + scs * sqrtf(tot));
  _Float16 o0 = (_Float16)(v0 * inv), o1 = (_Float16)(v1 * inv);
  muT[((size_t)b * KDIM + k) * CDIM + tid] = o0;
  muT[((size_t)b * KDIM + k) * CDIM + tid + 256] = o1;
  mu_ck[((size_t)b * CDIM + tid) * KDIM + k] = o0;
  mu_ck[((size_t)b * CDIM + tid + 256) * KDIM + k] = o1;
}

// ---------------------------------------------------------------------------
// Fused recon+conv2: per block (n-tile 128, batch b):
//  phase1: R[n][c] = relu(sum_k z[n][k] mu_ck[c][k]) into 128KB LDS (swizzled)
//  phase2: y16[o][n] = sum_c w2[o][c] R[n][c]; fused BN partial stats.
// 512 threads (8 waves), grid (N/128, B). mu/w2 read from global (L2-resident).
// ---------------------------------------------------------------------------
__global__ __launch_bounds__(512, 2) void k_rc2(
    const _Float16* __restrict__ z, const _Float16* __restrict__ mu_ck,
    const _Float16* __restrict__ w2, _Float16* __restrict__ y16,
    float* __restrict__ bnsum, float* __restrict__ bnsumsq) {
  __shared__ __align__(16) short R[128 * 512];  // 128 KB
  _Float16* Rh = (_Float16*)R;
  const int tid = threadIdx.x;
  const int l = tid & 63, w = tid >> 6;  // 8 waves
  const int lr = l & 15, lh = (l >> 4) & 3;
  const int n0 = blockIdx.x * 128;
  const int b = blockIdx.y;

  // ---- phase 1: wave w computes R rows [w*16, w*16+16) ----
  const short* zg = (const short*)(z + (size_t)b * NDIM * KDIM);
  const short* mg = (const short*)(mu_ck + (size_t)b * CDIM * KDIM);
  f16x8 zf[2];
  {
    const short* zrow = zg + (size_t)(n0 + w * 16 + lr) * KDIM;
#pragma unroll
    for (int kk = 0; kk < 2; ++kk)
      zf[kk] = *reinterpret_cast<const f16x8*>(zrow + kk * 32 + lh * 8);
  }
#pragma unroll
  for (int cc = 0; cc < 4; ++cc) {  // 128-c chunks
    f32x4 acc[8] = {};
#pragma unroll
    for (int kk = 0; kk < 2; ++kk) {
#pragma unroll
      for (int cf = 0; cf < 8; ++cf) {
        const short* mrow = mg + (size_t)(cc * 128 + cf * 16 + lr) * KDIM;
        f16x8 bf = *reinterpret_cast<const f16x8*>(mrow + kk * 32 + lh * 8);
        acc[cf] = __builtin_amdgcn_mfma_f32_16x16x32_f16(zf[kk], bf, acc[cf],
                                                         0, 0, 0);
      }
    }
#pragma unroll
    for (int cf = 0; cf < 8; ++cf) {
#pragma unroll
      for (int r = 0; r < 4; ++r) {
        int n = w * 16 + lh * 4 + r;
        int c = cc * 128 + cf * 16 + lr;
        Rh[n * 512 + ((c >> 3) ^ (n & 7)) * 8 + (c & 7)] =
            (_Float16)fmaxf(acc[cf][r], 0.f);
      }
    }
  }
  __syncthreads();

  // ---- phase 2: wave w computes y rows [w*64, w*64+64) for all 128 n ----
  const short* wg = (const short*)w2;
  _Float16* yb = y16 + (size_t)b * CDIM * NDIM;
  f32x4 acc2[4][8] = {};
  for (int cs = 0; cs < 8; ++cs) {  // 64-c steps
#pragma unroll
    for (int kk = 0; kk < 2; ++kk) {
      f16x8 af[4], bf[8];
#pragma unroll
      for (int mf = 0; mf < 4; ++mf) {
        const short* wrow = wg + (size_t)(w * 64 + mf * 16 + lr) * CDIM;
        af[mf] = *reinterpret_cast<const f16x8*>(wrow + cs * 64 + kk * 32 + lh * 8);
      }
#pragma unroll
      for (int nf = 0; nf < 8; ++nf) {
        int n = nf * 16 + lr;
        int slot = (cs * 8 + kk * 4 + lh) ^ (n & 7);
        bf[nf] = *reinterpret_cast<const f16x8*>(&R[n * 512 + slot * 8]);
      }
#pragma unroll
      for (int mf = 0; mf < 4; ++mf)
#pragma unroll
        for (int nf = 0; nf < 8; ++nf)
          acc2[mf][nf] = __builtin_amdgcn_mfma_f32_16x16x32_f16(
              af[mf], bf[nf], acc2[mf][nf], 0, 0, 0);
    }
  }
#pragma unroll
  for (int mf = 0; mf < 4; ++mf) {
#pragma unroll
    for (int r = 0; r < 4; ++r) {
      int o = w * 64 + mf * 16 + lh * 4 + r;
      float ps = 0.f, pq = 0.f;
#pragma unroll
      for (int nf = 0; nf < 8; ++nf) {
        float v = acc2[mf][nf][r];
        ps += v; pq += v * v;
        yb[(size_t)o * NDIM + n0 + nf * 16 + lr] = (_Float16)v;
      }
#pragma unroll
      for (int d = 1; d < 16; d <<= 1) {
        ps += __shfl_xor(ps, d);
        pq += __shfl_xor(pq, d);
      }
      if (lr == 0) {
        atomicAdd(&bnsum[o], ps);
        atomicAdd(&bnsumsq[o], pq);
      }
    }
  }
}

// ---------------------------------------------------------------------------
// final: out = relu((y-mean)*rsqrt(var+eps)*gamma + beta + x), y fp16
// ---------------------------------------------------------------------------
__global__ void k_final(float* __restrict__ out, const _Float16* __restrict__ y16,
                        const float* __restrict__ x,
                        const float* __restrict__ bnsum,
                        const float* __restrict__ bnsumsq,
                        const float* __restrict__ gamma,
                        const float* __restrict__ beta) {
  const float invM = 1.f / (BDIM * (float)NDIM);
  const size_t total4 = (size_t)BDIM * CDIM * NDIM / 4;
  for (size_t i4 = (size_t)blockIdx.x * 256 + threadIdx.x; i4 < total4;
       i4 += (size_t)gridDim.x * 256) {
    int c = (int)((i4 >> 10) & (CDIM - 1));
    float mean = bnsum[c] * invM;
    float var = bnsumsq[c] * invM - mean * mean;
    float sc = rsqrtf(var + 1e-5f) * gamma[c];
    float sh = beta[c] - mean * sc;
    f16x4 yv = *reinterpret_cast<const f16x4*>(&y16[i4 * 4]);
    float4 xv = reinterpret_cast<const float4*>(x)[i4];
    float4 o;
    o.x = fmaxf(fmaf((float)yv[0], sc, sh) + xv.x, 0.f);
    o.y = fmaxf(fmaf((float)yv[1], sc, sh) + xv.y, 0.f);
    o.z = fmaxf(fmaf((float)yv[2], sc, sh) + xv.z, 0.f);
    o.w = fmaxf(fmaf((float)yv[3], sc, sh) + xv.w, 0.f);
    reinterpret_cast<float4*>(out)[i4] = o;
  }
}

// ---------------------------------------------------------------------------
extern "C" void kernel_launch(void* const* d_in, const int* in_sizes, int n_in,
                              void* d_out, int out_size, void* d_ws,
                              size_t ws_size, hipStream_t stream) {
  const float* x = (const float*)d_in[0];
  const float* mu = (const float*)d_in[1];
  const float* w1 = (const float*)d_in[2];
  const float* b1 = (const float*)d_in[3];
  const float* w2 = (const float*)d_in[4];
  const float* gamma = (const float*)d_in[5];
  const float* beta = (const float*)d_in[6];
  float* out = (float*)d_out;

  // xf dual copies live in d_out until k_final overwrites it.
  _Float16* xfT = (_Float16*)d_out;              // [B][N][C]
  _Float16* xf = (_Float16*)d_out + 33554432;    // [B][C][N]

  _Float16* wsH = (_Float16*)d_ws;
  _Float16* xT = wsH;                            // [B][N][C]
  _Float16* z = wsH + 33554432;                  // [B][N][K]
  _Float16* zT = z + 4194304;                    // [B][K][N]
  _Float16* muT = zT + 4194304;                  // [B][K][C]
  _Float16* mu_ck = muT + 524288;                // [B][C][K]
  _Float16* w1h = mu_ck + 524288;                // [C][C]
  _Float16* w2h = w1h + 262144;
  float* wsF = (float*)(w2h + 262144);
  float* mupart = wsF;                           // [B][K][C] f32 (2 MB)
  float* colsum = mupart + 524288;               // [B][K]
  float* bnsum = colsum + 1024;                  // [C]
  float* bnsumsq = bnsum + 512;                  // [C]
  _Float16* y16 = (_Float16*)(bnsumsq + 512);    // [B][C][N] fp16

  k_cvtT16<<<dim3(NDIM / 64, CDIM / 64, BDIM), 256, 0, stream>>>(x, xT);
  k_cvt_w16<<<CDIM * CDIM / 1024, 256, 0, stream>>>(w1, w1h);
  k_cvt_w16<<<CDIM * CDIM / 1024, 256, 0, stream>>>(w2, w2h);

  k_conv1_16<<<dim3(NDIM / 128, CDIM / 128, BDIM), 256, 0, stream>>>(
      xT, w1h, b1, xfT, xf);
  k_init_mu16<<<2048, 256, 0, stream>>>(mu, muT);

  for (int s = 0; s < 3; ++s) {
    hipMemsetAsync(colsum, 0, 1024 * sizeof(float), stream);
    k_s1_16<<<dim3(NDIM / 128, BDIM), 256, 0, stream>>>(xfT, muT, z, zT, colsum);
    hipMemsetAsync(mupart, 0, 524288 * sizeof(float), stream);
    k_s2_16<<<dim3(CDIM / 128, NSPLIT, BDIM), 256, 0, stream>>>(zT, xf, mupart);
    k_s2red<<<KDIM * BDIM, 256, 0, stream>>>(mupart, colsum, muT, mu_ck);
  }

  hipMemsetAsync(bnsum, 0, 1024 * sizeof(float), stream);
  k_rc2<<<dim3(NDIM / 128, BDIM), 512, 0, stream>>>(z, mu_ck, w2h, y16, bnsum,
                                                    bnsumsq);

  k_final<<<4096, 256, 0, stream>>>(out, y16, x, bnsum, bnsumsq, gamma, beta);
}

// Round 8
// 403.742 us; speedup vs baseline: 1.1236x; 1.1232x over previous
//
#include <hip/hip_runtime.h>
#include <math.h>

#define CDIM 512
#define NDIM 4096
#define KDIM 64
#define BDIM 16
#define NSPLIT 8

typedef __attribute__((ext_vector_type(8))) _Float16 f16x8;
typedef __attribute__((ext_vector_type(4))) _Float16 f16x4;
typedef __attribute__((ext_vector_type(4))) float f32x4;

__device__ __forceinline__ void g2lds16(const void* g, void* l) {
  __builtin_amdgcn_global_load_lds(
      (const __attribute__((address_space(1))) int*)g,
      (__attribute__((address_space(3))) int*)l, 16, 0, 0);
}

__device__ __forceinline__ f16x8 ldsfrag(const short* base, int row, int kk,
                                         int lh) {
  int slot = (kk * 4 + lh) ^ (row & 7);
  return *reinterpret_cast<const f16x8*>(&base[row * 64 + slot * 8]);
}

// ---------------------------------------------------------------------------
// weights f32 -> fp16
// ---------------------------------------------------------------------------
__global__ void k_cvt_w16(const float* __restrict__ w,
                          _Float16* __restrict__ wh) {
  int i = (blockIdx.x * 256 + threadIdx.x) * 4;
  float4 v = *reinterpret_cast<const float4*>(&w[i]);
  wh[i] = (_Float16)v.x; wh[i + 1] = (_Float16)v.y;
  wh[i + 2] = (_Float16)v.z; wh[i + 3] = (_Float16)v.w;
}

// ---------------------------------------------------------------------------
// conv1 (fused f32->fp16 convert): xf = W1*x + b1, dual-layout output:
//   xfT[b][n][o] fp16 (scalar writes) and xf[b][o][n] fp16 (via LDS transpose)
// A-tile staged from x f32 directly: per K-step, thread (n = tid&127,
// cg = tid>>7) loads 32 dwords x[c0+cg*32+j][i0+n] (lane-coalesced along n),
// converts, writes 4x ds_write_b128 at swizzled slot (c>>3)^(n&7) — the same
// involution ldsfrag reads. grid (N/128, C/128, B); 4 waves.
// ---------------------------------------------------------------------------
__global__ __launch_bounds__(256) void k_conv1_16(
    const float* __restrict__ x, const _Float16* __restrict__ w1,
    const float* __restrict__ b1, _Float16* __restrict__ xfT,
    _Float16* __restrict__ xf) {
  __shared__ __align__(16) short smem[17408];  // At[8192] Bt[8192]; Ot overlays
  short* At = smem;
  short* Bt = smem + 8192;
  const int tid = threadIdx.x;
  const int l = tid & 63, w = tid >> 6;
  const int wm = w >> 1, wn = w & 1;
  const int lr = l & 15, lh = l >> 4;
  const int i0 = blockIdx.x * 128;  // n
  const int j0 = blockIdx.y * 128;  // o
  const int b = blockIdx.z;
  const float* xg = x + (size_t)b * CDIM * NDIM;
  const short* Bg = (const short*)w1;
  const int an = tid & 127;        // A-staging: this thread's n row
  const int acg = tid >> 7;        // c-group (0/1): c in [acg*32, acg*32+32)
  f32x4 acc[4][4] = {};
  for (int c0 = 0; c0 < CDIM; c0 += 64) {
    // ---- A: convert-transpose from x f32 ----
#pragma unroll
    for (int cb = 0; cb < 4; ++cb) {
      int c = acg * 32 + cb * 8;
      f16x8 h;
#pragma unroll
      for (int j = 0; j < 8; ++j)
        h[j] = (_Float16)xg[(size_t)(c0 + c + j) * NDIM + i0 + an];
      int sp = ((c >> 3) ^ (an & 7));
      *reinterpret_cast<f16x8*>(&At[an * 64 + sp * 8]) = h;
    }
    // ---- B: w1 fp16 via global_load_lds (pre-swizzled source) ----
#pragma unroll
    for (int i = 0; i < 4; ++i) {
      int slot = i * 256 + tid;
      int r = slot >> 3, s = slot & 7, sp = s ^ (r & 7);
      g2lds16(Bg + (size_t)(j0 + r) * CDIM + c0 + sp * 8, Bt + slot * 8);
    }
    __syncthreads();
#pragma unroll
    for (int kk = 0; kk < 2; ++kk) {
      f16x8 af[4], bf[4];
#pragma unroll
      for (int m = 0; m < 4; ++m) af[m] = ldsfrag(At, wm * 64 + m * 16 + lr, kk, lh);
#pragma unroll
      for (int nf = 0; nf < 4; ++nf) bf[nf] = ldsfrag(Bt, wn * 64 + nf * 16 + lr, kk, lh);
#pragma unroll
      for (int m = 0; m < 4; ++m)
#pragma unroll
        for (int nf = 0; nf < 4; ++nf)
          acc[m][nf] = __builtin_amdgcn_mfma_f32_16x16x32_f16(af[m], bf[nf],
                                                              acc[m][nf], 0, 0, 0);
    }
    __syncthreads();
  }
  // Epilogue: xfT scalar writes + scatter into Ot[o][n] (pad 136)
  _Float16* Otf = (_Float16*)smem;
  _Float16* ob = xfT + (size_t)b * NDIM * CDIM;
#pragma unroll
  for (int m = 0; m < 4; ++m) {
#pragma unroll
    for (int nf = 0; nf < 4; ++nf) {
      int ol = wn * 64 + nf * 16 + lr;
      float bv = b1[j0 + ol];
#pragma unroll
      for (int r = 0; r < 4; ++r) {
        int nl = wm * 64 + m * 16 + lh * 4 + r;
        _Float16 hv = (_Float16)(acc[m][nf][r] + bv);
        ob[(size_t)(i0 + nl) * CDIM + j0 + ol] = hv;
        Otf[ol * 136 + nl] = hv;
      }
    }
  }
  __syncthreads();
  _Float16* xfb = xf + (size_t)b * CDIM * NDIM;
#pragma unroll
  for (int i = 0; i < 8; ++i) {
    int seg = i * 256 + tid;
    int row = seg >> 4, cs = seg & 15;
    f16x8 v = *reinterpret_cast<const f16x8*>(&Otf[row * 136 + cs * 8]);
    *reinterpret_cast<f16x8*>(&xfb[(size_t)(j0 + row) * NDIM + i0 + cs * 8]) = v;
  }
}

// ---------------------------------------------------------------------------
// conv2: y16[b][o][n] fp16 = sum_c w2[o][c] reconT[n][c]; fused BN partial
// stats.  grid (N/128, C/128, B) — n on x so blocks sharing a reconT tile
// land on the same XCD (ids differ by 32, 32%8==0).
// ---------------------------------------------------------------------------
__global__ __launch_bounds__(256) void k_conv2_16(
    const _Float16* __restrict__ w2, const _Float16* __restrict__ reconT,
    _Float16* __restrict__ y16, float* __restrict__ bnsum,
    float* __restrict__ bnsumsq) {
  __shared__ __align__(16) short At[128 * 64];
  __shared__ __align__(16) short Bt[128 * 64];
  __shared__ float bns[128], bnq[128];
  const int tid = threadIdx.x;
  const int l = tid & 63, w = tid >> 6;
  const int wm = w >> 1, wn = w & 1;
  const int lr = l & 15, lh = l >> 4;
  const int i0 = blockIdx.y * 128;  // o
  const int j0 = blockIdx.x * 128;  // n
  const int b = blockIdx.z;
  if (tid < 128) { bns[tid] = 0.f; bnq[tid] = 0.f; }
  const short* Ag = (const short*)w2;
  const short* Bg = (const short*)(reconT + (size_t)b * NDIM * CDIM);
  f32x4 acc[4][4] = {};
  for (int c0 = 0; c0 < CDIM; c0 += 64) {
#pragma unroll
    for (int i = 0; i < 4; ++i) {
      int slot = i * 256 + tid;
      int r = slot >> 3, s = slot & 7, sp = s ^ (r & 7);
      g2lds16(Ag + (size_t)(i0 + r) * CDIM + c0 + sp * 8, At + slot * 8);
    }
#pragma unroll
    for (int i = 0; i < 4; ++i) {
      int slot = i * 256 + tid;
      int r = slot >> 3, s = slot & 7, sp = s ^ (r & 7);
      g2lds16(Bg + (size_t)(j0 + r) * CDIM + c0 + sp * 8, Bt + slot * 8);
    }
    __syncthreads();
#pragma unroll
    for (int kk = 0; kk < 2; ++kk) {
      f16x8 af[4], bf[4];
#pragma unroll
      for (int m = 0; m < 4; ++m) af[m] = ldsfrag(At, wm * 64 + m * 16 + lr, kk, lh);
#pragma unroll
      for (int nf = 0; nf < 4; ++nf) bf[nf] = ldsfrag(Bt, wn * 64 + nf * 16 + lr, kk, lh);
#pragma unroll
      for (int m = 0; m < 4; ++m)
#pragma unroll
        for (int nf = 0; nf < 4; ++nf)
          acc[m][nf] = __builtin_amdgcn_mfma_f32_16x16x32_f16(af[m], bf[nf],
                                                              acc[m][nf], 0, 0, 0);
    }
    __syncthreads();
  }
  _Float16* yb = y16 + (size_t)b * CDIM * NDIM;
#pragma unroll
  for (int m = 0; m < 4; ++m) {
#pragma unroll
    for (int r = 0; r < 4; ++r) {
      int ol = wm * 64 + m * 16 + lh * 4 + r;
      float ps = 0.f, pq = 0.f;
#pragma unroll
      for (int nf = 0; nf < 4; ++nf) {
        float v = acc[m][nf][r];
        ps += v; pq += v * v;
        yb[(size_t)(i0 + ol) * NDIM + j0 + wn * 64 + nf * 16 + lr] = (_Float16)v;
      }
#pragma unroll
      for (int d = 1; d < 16; d <<= 1) {
        ps += __shfl_xor(ps, d);
        pq += __shfl_xor(pq, d);
      }
      if (lr == 0) { atomicAdd(&bns[ol], ps); atomicAdd(&bnq[ol], pq); }
    }
  }
  __syncthreads();
  if (tid < 128) {
    atomicAdd(&bnsum[i0 + tid], bns[tid]);
    atomicAdd(&bnsumsq[i0 + tid], bnq[tid]);
  }
}

// ---------------------------------------------------------------------------
// init muT[b][k][c] fp16 = mu[c][k]
// ---------------------------------------------------------------------------
__global__ void k_init_mu16(const float* __restrict__ mu,
                            _Float16* __restrict__ muT) {
  int idx = blockIdx.x * 256 + threadIdx.x;  // 524288
  int rem = idx & 32767;
  int k = rem >> 9, c = rem & 511;
  muT[idx] = (_Float16)mu[c * KDIM + k];
}

// ---------------------------------------------------------------------------
// S1 (fp16 MFMA): logits[n][k] = sum_c xfT[n][c] muT[k][c]; z=softmax_k;
// writes z[b][n][k] (only if writeZ), zT[b][k][n] fp16, colsum[b][k].
// grid (N/128, B). 128n x 64k tile; 4 waves own 32 n-rows each.
// ---------------------------------------------------------------------------
__global__ __launch_bounds__(256) void k_s1_16(const _Float16* __restrict__ xfT,
                                               const _Float16* __restrict__ muT,
                                               _Float16* __restrict__ z,
                                               _Float16* __restrict__ zT,
                                               float* __restrict__ colsum,
                                               int writeZ) {
  __shared__ __align__(16) short At[128 * 64];
  __shared__ __align__(16) short Bt[64 * 64];
  __shared__ __align__(16) _Float16 zs[128][72];
  __shared__ float csum[4][64];
  const int tid = threadIdx.x;
  const int l = tid & 63, w = tid >> 6;
  const int lr = l & 15, lh = l >> 4;
  const int n0 = blockIdx.x * 128;
  const int b = blockIdx.y;
  const short* Ag = (const short*)(xfT + (size_t)b * NDIM * CDIM);
  const short* Bg = (const short*)(muT + (size_t)b * KDIM * CDIM);
  f32x4 acc[2][4] = {};
  for (int c0 = 0; c0 < CDIM; c0 += 64) {
#pragma unroll
    for (int i = 0; i < 4; ++i) {
      int slot = i * 256 + tid;
      int r = slot >> 3, s = slot & 7, sp = s ^ (r & 7);
      g2lds16(Ag + (size_t)(n0 + r) * CDIM + c0 + sp * 8, At + slot * 8);
    }
#pragma unroll
    for (int i = 0; i < 2; ++i) {
      int slot = i * 256 + tid;
      int r = slot >> 3, s = slot & 7, sp = s ^ (r & 7);
      g2lds16(Bg + (size_t)r * CDIM + c0 + sp * 8, Bt + slot * 8);
    }
    __syncthreads();
#pragma unroll
    for (int kk = 0; kk < 2; ++kk) {
      f16x8 af[2], bf;
#pragma unroll
      for (int nf = 0; nf < 2; ++nf)
        af[nf] = ldsfrag(At, w * 32 + nf * 16 + lr, kk, lh);
#pragma unroll
      for (int kf = 0; kf < 4; ++kf) {
        bf = ldsfrag(Bt, kf * 16 + lr, kk, lh);
#pragma unroll
        for (int nf = 0; nf < 2; ++nf)
          acc[nf][kf] = __builtin_amdgcn_mfma_f32_16x16x32_f16(af[nf], bf,
                                                               acc[nf][kf], 0, 0, 0);
      }
    }
    __syncthreads();
  }
#pragma unroll
  for (int nf = 0; nf < 2; ++nf) {
#pragma unroll
    for (int r = 0; r < 4; ++r) {
      float m = fmaxf(fmaxf(acc[nf][0][r], acc[nf][1][r]),
                      fmaxf(acc[nf][2][r], acc[nf][3][r]));
#pragma unroll
      for (int d = 8; d >= 1; d >>= 1) m = fmaxf(m, __shfl_xor(m, d));
      float e[4], s = 0.f;
#pragma unroll
      for (int kf = 0; kf < 4; ++kf) { e[kf] = __expf(acc[nf][kf][r] - m); s += e[kf]; }
#pragma unroll
      for (int d = 8; d >= 1; d >>= 1) s += __shfl_xor(s, d);
      float inv = 1.f / s;
      int row = w * 32 + nf * 16 + lh * 4 + r;
#pragma unroll
      for (int kf = 0; kf < 4; ++kf)
        zs[row][kf * 16 + lr] = (_Float16)(e[kf] * inv);
    }
  }
  __syncthreads();
  _Float16* zTb = zT + (size_t)b * KDIM * NDIM;
  if (writeZ) {
    _Float16* zb = z + (size_t)b * NDIM * KDIM;
#pragma unroll
    for (int i = 0; i < 4; ++i) {  // z[n][k]
      int idx = i * 256 + tid;
      int n = idx >> 3, ch = idx & 7;
      *reinterpret_cast<uint4*>(&zb[(size_t)(n0 + n) * KDIM + ch * 8]) =
          *reinterpret_cast<const uint4*>(&zs[n][ch * 8]);
    }
  }
#pragma unroll
  for (int i = 0; i < 4; ++i) {  // zT[k][n]
    int idx = i * 256 + tid;
    int k = idx >> 4, nch = idx & 15;
    f16x8 v;
#pragma unroll
    for (int j = 0; j < 8; ++j) v[j] = zs[nch * 8 + j][k];
    *reinterpret_cast<f16x8*>(&zTb[(size_t)k * NDIM + n0 + nch * 8]) = v;
  }
  {  // colsum: thread (q=tid>>6, k=tid&63) sums 32 rows
    int k = tid & 63, q = tid >> 6;
    float s = 0.f;
#pragma unroll
    for (int n = 0; n < 32; ++n) s += (float)zs[q * 32 + n][k];
    csum[q][k] = s;
  }
  __syncthreads();
  if (tid < 64)
    atomicAdd(&colsum[b * KDIM + tid],
              csum[0][tid] + csum[1][tid] + csum[2][tid] + csum[3][tid]);
}

// ---------------------------------------------------------------------------
// S2 (fp16 MFMA): mu_part[s][b][k][c] = sum_{n in split} zT[k][n] xf[c][n]
// grid (C/128, NSPLIT, B). 64k x 128c tile; 4 waves own 32 c-cols each.
// ---------------------------------------------------------------------------
__global__ __launch_bounds__(256) void k_s2_16(const _Float16* __restrict__ zT,
                                               const _Float16* __restrict__ xf,
                                               float* __restrict__ mupart) {
  __shared__ __align__(16) short At[64 * 64];
  __shared__ __align__(16) short Bt[128 * 64];
  const int tid = threadIdx.x;
  const int l = tid & 63, w = tid >> 6;
  const int lr = l & 15, lh = l >> 4;
  const int c0 = blockIdx.x * 128;
  const int split = blockIdx.y;
  const int b = blockIdx.z;
  const short* Ag = (const short*)(zT + (size_t)b * KDIM * NDIM);
  const short* Bg = (const short*)(xf + (size_t)b * CDIM * NDIM);
  f32x4 acc[4][2] = {};
  for (int st = 0; st < 8; ++st) {
    const int nb = split * (NDIM / NSPLIT) + st * 64;
#pragma unroll
    for (int i = 0; i < 2; ++i) {
      int slot = i * 256 + tid;
      int r = slot >> 3, s = slot & 7, sp = s ^ (r & 7);
      g2lds16(Ag + (size_t)r * NDIM + nb + sp * 8, At + slot * 8);
    }
#pragma unroll
    for (int i = 0; i < 4; ++i) {
      int slot = i * 256 + tid;
      int r = slot >> 3, s = slot & 7, sp = s ^ (r & 7);
      g2lds16(Bg + (size_t)(c0 + r) * NDIM + nb + sp * 8, Bt + slot * 8);
    }
    __syncthreads();
#pragma unroll
    for (int kk = 0; kk < 2; ++kk) {
      f16x8 bf[2], af;
#pragma unroll
      for (int cf = 0; cf < 2; ++cf)
        bf[cf] = ldsfrag(Bt, w * 32 + cf * 16 + lr, kk, lh);
#pragma unroll
      for (int kf = 0; kf < 4; ++kf) {
        af = ldsfrag(At, kf * 16 + lr, kk, lh);
#pragma unroll
        for (int cf = 0; cf < 2; ++cf)
          acc[kf][cf] = __builtin_amdgcn_mfma_f32_16x16x32_f16(af, bf[cf],
                                                               acc[kf][cf], 0, 0, 0);
      }
    }
    __syncthreads();
  }
  float* mp = mupart + ((size_t)(split * BDIM + b) * KDIM) * CDIM;
#pragma unroll
  for (int kf = 0; kf < 4; ++kf) {
    int k = kf * 16 + lh * 4;
#pragma unroll
    for (int r = 0; r < 4; ++r)
#pragma unroll
      for (int cf = 0; cf < 2; ++cf)
        mp[(size_t)(k + r) * CDIM + c0 + w * 32 + cf * 16 + lr] = acc[kf][cf][r];
  }
}

// ---------------------------------------------------------------------------
// S2 reduce: v[c] = sum_s mu_part; t = v*scs[k]; out = t/(1e-6+|t|_2)
// ---------------------------------------------------------------------------
__global__ __launch_bounds__(256) void k_s2red(const float* __restrict__ mupart,
                                               const float* __restrict__ colsum,
                                               _Float16* __restrict__ muT,
                                               _Float16* __restrict__ mu_ck) {
  __shared__ float red[4];
  const int tid = threadIdx.x;
  const int b = blockIdx.x >> 6, k = blockIdx.x & 63;
  float v0 = 0.f, v1 = 0.f;
#pragma unroll
  for (int s = 0; s < NSPLIT; ++s) {
    const float* mp = mupart + ((size_t)(s * BDIM + b) * KDIM + k) * CDIM;
    v0 += mp[tid];
    v1 += mp[tid + 256];
  }
  float ssq = v0 * v0 + v1 * v1;
#pragma unroll
  for (int d = 32; d >= 1; d >>= 1) ssq += __shfl_down(ssq, d);
  if ((tid & 63) == 0) red[tid >> 6] = ssq;
  __syncthreads();
  float tot = red[0] + red[1] + red[2] + red[3];
  float scs = 1.f / (1e-6f + colsum[b * KDIM + k]);
  float inv = scs / (1e-6f + scs * sqrtf(tot));
  _Float16 o0 = (_Float16)(v0 * inv), o1 = (_Float16)(v1 * inv);
  muT[((size_t)b * KDIM + k) * CDIM + tid] = o0;
  muT[((size_t)b * KDIM + k) * CDIM + tid + 256] = o1;
  mu_ck[((size_t)b * CDIM + tid) * KDIM + k] = o0;
  mu_ck[((size_t)b * CDIM + tid + 256) * KDIM + k] = o1;
}

// ---------------------------------------------------------------------------
// recon (fp16 MFMA): reconT[n][c] = relu(sum_k z[n][k] mu_ck[c][k])
// grid (N/128, C/128, B)
// ---------------------------------------------------------------------------
__global__ __launch_bounds__(256) void k_recon16(const _Float16* __restrict__ z,
                                                 const _Float16* __restrict__ mu_ck,
                                                 _Float16* __restrict__ reconT) {
  __shared__ __align__(16) short Az[128 * 64];
  __shared__ __align__(16) short Bm[128 * 64];
  const int tid = threadIdx.x;
  const int l = tid & 63, w = tid >> 6;
  const int wm = w >> 1, wn = w & 1;
  const int lr = l & 15, lh = l >> 4;
  const int n0 = blockIdx.x * 128;
  const int c0 = blockIdx.y * 128;
  const int b = blockIdx.z;
  const short* Ag = (const short*)(z + (size_t)b * NDIM * KDIM);
  const short* Bg = (const short*)(mu_ck + (size_t)b * CDIM * KDIM);
#pragma unroll
  for (int i = 0; i < 4; ++i) {
    int slot = i * 256 + tid;
    int r = slot >> 3, s = slot & 7, sp = s ^ (r & 7);
    g2lds16(Ag + (size_t)(n0 + r) * KDIM + sp * 8, Az + slot * 8);
  }
#pragma unroll
  for (int i = 0; i < 4; ++i) {
    int slot = i * 256 + tid;
    int r = slot >> 3, s = slot & 7, sp = s ^ (r & 7);
    g2lds16(Bg + (size_t)(c0 + r) * KDIM + sp * 8, Bm + slot * 8);
  }
  __syncthreads();
  f32x4 acc[4][4] = {};
#pragma unroll
  for (int kk = 0; kk < 2; ++kk) {
    f16x8 af[4], bf[4];
#pragma unroll
    for (int m = 0; m < 4; ++m) af[m] = ldsfrag(Az, wm * 64 + m * 16 + lr, kk, lh);
#pragma unroll
    for (int nf = 0; nf < 4; ++nf) bf[nf] = ldsfrag(Bm, wn * 64 + nf * 16 + lr, kk, lh);
#pragma unroll
    for (int m = 0; m < 4; ++m)
#pragma unroll
      for (int nf = 0; nf < 4; ++nf)
        acc[m][nf] = __builtin_amdgcn_mfma_f32_16x16x32_f16(af[m], bf[nf],
                                                            acc[m][nf], 0, 0, 0);
  }
  _Float16* ob = reconT + (size_t)b * NDIM * CDIM;
#pragma unroll
  for (int m = 0; m < 4; ++m) {
#pragma unroll
    for (int r = 0; r < 4; ++r) {
      int n = n0 + wm * 64 + m * 16 + lh * 4 + r;
#pragma unroll
      for (int nf = 0; nf < 4; ++nf) {
        int c = c0 + wn * 64 + nf * 16 + lr;
        ob[(size_t)n * CDIM + c] = (_Float16)fmaxf(acc[m][nf][r], 0.f);
      }
    }
  }
}

// ---------------------------------------------------------------------------
// final: out = relu((y-mean)*rsqrt(var+eps)*gamma + beta + x), y fp16
// ---------------------------------------------------------------------------
__global__ void k_final(float* __restrict__ out, const _Float16* __restrict__ y16,
                        const float* __restrict__ x,
                        const float* __restrict__ bnsum,
                        const float* __restrict__ bnsumsq,
                        const float* __restrict__ gamma,
                        const float* __restrict__ beta) {
  const float invM = 1.f / (BDIM * (float)NDIM);
  const size_t total4 = (size_t)BDIM * CDIM * NDIM / 4;
  for (size_t i4 = (size_t)blockIdx.x * 256 + threadIdx.x; i4 < total4;
       i4 += (size_t)gridDim.x * 256) {
    int c = (int)((i4 >> 10) & (CDIM - 1));
    float mean = bnsum[c] * invM;
    float var = bnsumsq[c] * invM - mean * mean;
    float sc = rsqrtf(var + 1e-5f) * gamma[c];
    float sh = beta[c] - mean * sc;
    f16x4 yv = *reinterpret_cast<const f16x4*>(&y16[i4 * 4]);
    float4 xv = reinterpret_cast<const float4*>(x)[i4];
    float4 o;
    o.x = fmaxf(fmaf((float)yv[0], sc, sh) + xv.x, 0.f);
    o.y = fmaxf(fmaf((float)yv[1], sc, sh) + xv.y, 0.f);
    o.z = fmaxf(fmaf((float)yv[2], sc, sh) + xv.z, 0.f);
    o.w = fmaxf(fmaf((float)yv[3], sc, sh) + xv.w, 0.f);
    reinterpret_cast<float4*>(out)[i4] = o;
  }
}

// ---------------------------------------------------------------------------
extern "C" void kernel_launch(void* const* d_in, const int* in_sizes, int n_in,
                              void* d_out, int out_size, void* d_ws,
                              size_t ws_size, hipStream_t stream) {
  const float* x = (const float*)d_in[0];
  const float* mu = (const float*)d_in[1];
  const float* w1 = (const float*)d_in[2];
  const float* b1 = (const float*)d_in[3];
  const float* w2 = (const float*)d_in[4];
  const float* gamma = (const float*)d_in[5];
  const float* beta = (const float*)d_in[6];
  float* out = (float*)d_out;

  // xf dual copies live in d_out until k_final overwrites it.
  _Float16* xfT = (_Float16*)d_out;              // [B][N][C]
  _Float16* xf = (_Float16*)d_out + 33554432;    // [B][C][N]

  _Float16* wsH = (_Float16*)d_ws;
  _Float16* reconT = wsH;                        // [B][N][C]
  _Float16* z = wsH + 33554432;                  // [B][N][K]
  _Float16* zT = z + 4194304;                    // [B][K][N]
  _Float16* muT = zT + 4194304;                  // [B][K][C]
  _Float16* mu_ck = muT + 524288;                // [B][C][K]
  _Float16* w1h = mu_ck + 524288;                // [C][C]
  _Float16* w2h = w1h + 262144;
  float* wsF = (float*)(w2h + 262144);
  float* mupart = wsF;                           // [S][B][K][C] f32
  float* colsum = mupart + 4194304;              // [B][K]
  float* bnsum = colsum + 1024;                  // [C]
  float* bnsumsq = bnsum + 512;                  // [C]
  _Float16* y16 = (_Float16*)(bnsumsq + 512);    // [B][C][N] fp16

  k_cvt_w16<<<CDIM * CDIM / 1024, 256, 0, stream>>>(w1, w1h);
  k_cvt_w16<<<CDIM * CDIM / 1024, 256, 0, stream>>>(w2, w2h);

  k_conv1_16<<<dim3(NDIM / 128, CDIM / 128, BDIM), 256, 0, stream>>>(
      x, w1h, b1, xfT, xf);
  k_init_mu16<<<2048, 256, 0, stream>>>(mu, muT);

  for (int s = 0; s < 3; ++s) {
    hipMemsetAsync(colsum, 0, 1024 * sizeof(float), stream);
    k_s1_16<<<dim3(NDIM / 128, BDIM), 256, 0, stream>>>(xfT, muT, z, zT, colsum,
                                                        s == 2 ? 1 : 0);
    k_s2_16<<<dim3(CDIM / 128, NSPLIT, BDIM), 256, 0, stream>>>(zT, xf, mupart);
    k_s2red<<<KDIM * BDIM, 256, 0, stream>>>(mupart, colsum, muT, mu_ck);
  }

  k_recon16<<<dim3(NDIM / 128, CDIM / 128, BDIM), 256, 0, stream>>>(z, mu_ck,
                                                                    reconT);
  hipMemsetAsync(bnsum, 0, 1024 * sizeof(float), stream);
  k_conv2_16<<<dim3(NDIM / 128, CDIM / 128, BDIM), 256, 0, stream>>>(
      w2h, reconT, y16, bnsum, bnsumsq);

  k_final<<<4096, 256, 0, stream>>>(out, y16, x, bnsum, bnsumsq, gamma, beta);
}

// Round 9
// 384.804 us; speedup vs baseline: 1.1789x; 1.0492x over previous
//
#include <hip/hip_runtime.h>
#include <math.h>

#define CDIM 512
#define NDIM 4096
#define KDIM 64
#define BDIM 16
#define NSPLIT 4

typedef __attribute__((ext_vector_type(8))) _Float16 f16x8;
typedef __attribute__((ext_vector_type(4))) _Float16 f16x4;
typedef __attribute__((ext_vector_type(4))) float f32x4;

__device__ __forceinline__ void g2lds16(const void* g, void* l) {
  __builtin_amdgcn_global_load_lds(
      (const __attribute__((address_space(1))) int*)g,
      (__attribute__((address_space(3))) int*)l, 16, 0, 0);
}

__device__ __forceinline__ f16x8 ldsfrag(const short* base, int row, int kk,
                                         int lh) {
  int slot = (kk * 4 + lh) ^ (row & 7);
  return *reinterpret_cast<const f16x8*>(&base[row * 64 + slot * 8]);
}

// ---------------------------------------------------------------------------
// x [b][c][n] f32 -> xT [b][n][c] fp16.  grid (N/64, C/64, B)
// ---------------------------------------------------------------------------
__global__ __launch_bounds__(256) void k_cvtT16(const float* __restrict__ in,
                                                _Float16* __restrict__ outT) {
  __shared__ __align__(16) _Float16 T[64][80];
  const int t = threadIdx.x;
  const int n0 = blockIdx.x * 64, c0 = blockIdx.y * 64;
  const float* ib = in + (size_t)blockIdx.z * CDIM * NDIM;
  _Float16* ob = outT + (size_t)blockIdx.z * NDIM * CDIM;
#pragma unroll
  for (int i = 0; i < 4; ++i) {
    int idx = i * 256 + t;
    int cl = idx >> 4, f4 = idx & 15;
    float4 v = *reinterpret_cast<const float4*>(
        &ib[(size_t)(c0 + cl) * NDIM + n0 + f4 * 4]);
    T[f4 * 4 + 0][cl] = (_Float16)v.x;
    T[f4 * 4 + 1][cl] = (_Float16)v.y;
    T[f4 * 4 + 2][cl] = (_Float16)v.z;
    T[f4 * 4 + 3][cl] = (_Float16)v.w;
  }
  __syncthreads();
#pragma unroll
  for (int i = 0; i < 2; ++i) {
    int idx = i * 256 + t;
    int nl = idx >> 3, ch = idx & 7;
    uint4 u = *reinterpret_cast<const uint4*>(&T[nl][ch * 8]);
    *reinterpret_cast<uint4*>(&ob[(size_t)(n0 + nl) * CDIM + c0 + ch * 8]) = u;
  }
}

// ---------------------------------------------------------------------------
// weights f32 -> fp16
// ---------------------------------------------------------------------------
__global__ void k_cvt_w16(const float* __restrict__ w,
                          _Float16* __restrict__ wh) {
  int i = (blockIdx.x * 256 + threadIdx.x) * 4;
  float4 v = *reinterpret_cast<const float4*>(&w[i]);
  wh[i] = (_Float16)v.x; wh[i + 1] = (_Float16)v.y;
  wh[i + 2] = (_Float16)v.z; wh[i + 3] = (_Float16)v.w;
}

// ---------------------------------------------------------------------------
// conv1: xf = W1*x + b1, dual-layout output:
//   xfT[b][n][o] fp16 (scalar writes) and xf[b][o][n] fp16 (via LDS transpose)
// grid (N/128, C/128, B); 128x128 tile, BK=64, 4 waves.
// ---------------------------------------------------------------------------
__global__ __launch_bounds__(256) void k_conv1_16(
    const _Float16* __restrict__ xT, const _Float16* __restrict__ w1,
    const float* __restrict__ b1, _Float16* __restrict__ xfT,
    _Float16* __restrict__ xf) {
  __shared__ __align__(16) short smem[17408];  // At[8192] Bt[8192]; Ot overlays
  short* At = smem;
  short* Bt = smem + 8192;
  const int tid = threadIdx.x;
  const int l = tid & 63, w = tid >> 6;
  const int wm = w >> 1, wn = w & 1;
  const int lr = l & 15, lh = l >> 4;
  const int i0 = blockIdx.x * 128;  // n
  const int j0 = blockIdx.y * 128;  // o
  const int b = blockIdx.z;
  const short* Ag = (const short*)(xT + (size_t)b * NDIM * CDIM);
  const short* Bg = (const short*)w1;
  f32x4 acc[4][4] = {};
  for (int c0 = 0; c0 < CDIM; c0 += 64) {
#pragma unroll
    for (int i = 0; i < 4; ++i) {
      int slot = i * 256 + tid;
      int r = slot >> 3, s = slot & 7, sp = s ^ (r & 7);
      g2lds16(Ag + (size_t)(i0 + r) * CDIM + c0 + sp * 8, At + slot * 8);
    }
#pragma unroll
    for (int i = 0; i < 4; ++i) {
      int slot = i * 256 + tid;
      int r = slot >> 3, s = slot & 7, sp = s ^ (r & 7);
      g2lds16(Bg + (size_t)(j0 + r) * CDIM + c0 + sp * 8, Bt + slot * 8);
    }
    __syncthreads();
#pragma unroll
    for (int kk = 0; kk < 2; ++kk) {
      f16x8 af[4], bf[4];
#pragma unroll
      for (int m = 0; m < 4; ++m) af[m] = ldsfrag(At, wm * 64 + m * 16 + lr, kk, lh);
#pragma unroll
      for (int nf = 0; nf < 4; ++nf) bf[nf] = ldsfrag(Bt, wn * 64 + nf * 16 + lr, kk, lh);
#pragma unroll
      for (int m = 0; m < 4; ++m)
#pragma unroll
        for (int nf = 0; nf < 4; ++nf)
          acc[m][nf] = __builtin_amdgcn_mfma_f32_16x16x32_f16(af[m], bf[nf],
                                                              acc[m][nf], 0, 0, 0);
    }
    __syncthreads();
  }
  // Epilogue: xfT scalar writes + scatter into Ot[o][n] (pad 136)
  _Float16* Otf = (_Float16*)smem;
  _Float16* ob = xfT + (size_t)b * NDIM * CDIM;
#pragma unroll
  for (int m = 0; m < 4; ++m) {
#pragma unroll
    for (int nf = 0; nf < 4; ++nf) {
      int ol = wn * 64 + nf * 16 + lr;
      float bv = b1[j0 + ol];
#pragma unroll
      for (int r = 0; r < 4; ++r) {
        int nl = wm * 64 + m * 16 + lh * 4 + r;
        _Float16 hv = (_Float16)(acc[m][nf][r] + bv);
        ob[(size_t)(i0 + nl) * CDIM + j0 + ol] = hv;
        Otf[ol * 136 + nl] = hv;
      }
    }
  }
  __syncthreads();
  _Float16* xfb = xf + (size_t)b * CDIM * NDIM;
#pragma unroll
  for (int i = 0; i < 8; ++i) {
    int seg = i * 256 + tid;
    int row = seg >> 4, cs = seg & 15;
    f16x8 v = *reinterpret_cast<const f16x8*>(&Otf[row * 136 + cs * 8]);
    *reinterpret_cast<f16x8*>(&xfb[(size_t)(j0 + row) * NDIM + i0 + cs * 8]) = v;
  }
}

// ---------------------------------------------------------------------------
// conv2: y16[b][o][n] fp16 = sum_c w2[o][c] reconT[n][c]; fused BN partial
// stats.  grid (N/128, C/128, B) — n on x so blocks sharing a reconT tile
// land on the same XCD (ids differ by 32, 32%8==0).
// ---------------------------------------------------------------------------
__global__ __launch_bounds__(256) void k_conv2_16(
    const _Float16* __restrict__ w2, const _Float16* __restrict__ reconT,
    _Float16* __restrict__ y16, float* __restrict__ bnsum,
    float* __restrict__ bnsumsq) {
  __shared__ __align__(16) short At[128 * 64];
  __shared__ __align__(16) short Bt[128 * 64];
  __shared__ float bns[128], bnq[128];
  const int tid = threadIdx.x;
  const int l = tid & 63, w = tid >> 6;
  const int wm = w >> 1, wn = w & 1;
  const int lr = l & 15, lh = l >> 4;
  const int i0 = blockIdx.y * 128;  // o
  const int j0 = blockIdx.x * 128;  // n
  const int b = blockIdx.z;
  if (tid < 128) { bns[tid] = 0.f; bnq[tid] = 0.f; }
  const short* Ag = (const short*)w2;
  const short* Bg = (const short*)(reconT + (size_t)b * NDIM * CDIM);
  f32x4 acc[4][4] = {};
  for (int c0 = 0; c0 < CDIM; c0 += 64) {
#pragma unroll
    for (int i = 0; i < 4; ++i) {
      int slot = i * 256 + tid;
      int r = slot >> 3, s = slot & 7, sp = s ^ (r & 7);
      g2lds16(Ag + (size_t)(i0 + r) * CDIM + c0 + sp * 8, At + slot * 8);
    }
#pragma unroll
    for (int i = 0; i < 4; ++i) {
      int slot = i * 256 + tid;
      int r = slot >> 3, s = slot & 7, sp = s ^ (r & 7);
      g2lds16(Bg + (size_t)(j0 + r) * CDIM + c0 + sp * 8, Bt + slot * 8);
    }
    __syncthreads();
#pragma unroll
    for (int kk = 0; kk < 2; ++kk) {
      f16x8 af[4], bf[4];
#pragma unroll
      for (int m = 0; m < 4; ++m) af[m] = ldsfrag(At, wm * 64 + m * 16 + lr, kk, lh);
#pragma unroll
      for (int nf = 0; nf < 4; ++nf) bf[nf] = ldsfrag(Bt, wn * 64 + nf * 16 + lr, kk, lh);
#pragma unroll
      for (int m = 0; m < 4; ++m)
#pragma unroll
        for (int nf = 0; nf < 4; ++nf)
          acc[m][nf] = __builtin_amdgcn_mfma_f32_16x16x32_f16(af[m], bf[nf],
                                                              acc[m][nf], 0, 0, 0);
    }
    __syncthreads();
  }
  _Float16* yb = y16 + (size_t)b * CDIM * NDIM;
#pragma unroll
  for (int m = 0; m < 4; ++m) {
#pragma unroll
    for (int r = 0; r < 4; ++r) {
      int ol = wm * 64 + m * 16 + lh * 4 + r;
      float ps = 0.f, pq = 0.f;
#pragma unroll
      for (int nf = 0; nf < 4; ++nf) {
        float v = acc[m][nf][r];
        ps += v; pq += v * v;
        yb[(size_t)(i0 + ol) * NDIM + j0 + wn * 64 + nf * 16 + lr] = (_Float16)v;
      }
#pragma unroll
      for (int d = 1; d < 16; d <<= 1) {
        ps += __shfl_xor(ps, d);
        pq += __shfl_xor(pq, d);
      }
      if (lr == 0) { atomicAdd(&bns[ol], ps); atomicAdd(&bnq[ol], pq); }
    }
  }
  __syncthreads();
  if (tid < 128) {
    atomicAdd(&bnsum[i0 + tid], bns[tid]);
    atomicAdd(&bnsumsq[i0 + tid], bnq[tid]);
  }
}

// ---------------------------------------------------------------------------
// init muT[b][k][c] fp16 = mu[c][k]
// ---------------------------------------------------------------------------
__global__ void k_init_mu16(const float* __restrict__ mu,
                            _Float16* __restrict__ muT) {
  int idx = blockIdx.x * 256 + threadIdx.x;  // 524288
  int rem = idx & 32767;
  int k = rem >> 9, c = rem & 511;
  muT[idx] = (_Float16)mu[c * KDIM + k];
}

// ---------------------------------------------------------------------------
// S1 (fp16 MFMA): logits[n][k] = sum_c xfT[n][c] muT[k][c]; z=softmax_k;
// writes z[b][n][k] (only if writeZ), zT[b][k][n] fp16, colsum[b][k].
// grid (N/128, B). 128n x 64k tile; 4 waves own 32 n-rows each.
// ---------------------------------------------------------------------------
__global__ __launch_bounds__(256) void k_s1_16(const _Float16* __restrict__ xfT,
                                               const _Float16* __restrict__ muT,
                                               _Float16* __restrict__ z,
                                               _Float16* __restrict__ zT,
                                               float* __restrict__ colsum,
                                               int writeZ) {
  __shared__ __align__(16) short At[128 * 64];
  __shared__ __align__(16) short Bt[64 * 64];
  __shared__ __align__(16) _Float16 zs[128][72];
  __shared__ float csum[4][64];
  const int tid = threadIdx.x;
  const int l = tid & 63, w = tid >> 6;
  const int lr = l & 15, lh = l >> 4;
  const int n0 = blockIdx.x * 128;
  const int b = blockIdx.y;
  const short* Ag = (const short*)(xfT + (size_t)b * NDIM * CDIM);
  const short* Bg = (const short*)(muT + (size_t)b * KDIM * CDIM);
  f32x4 acc[2][4] = {};
  for (int c0 = 0; c0 < CDIM; c0 += 64) {
#pragma unroll
    for (int i = 0; i < 4; ++i) {
      int slot = i * 256 + tid;
      int r = slot >> 3, s = slot & 7, sp = s ^ (r & 7);
      g2lds16(Ag + (size_t)(n0 + r) * CDIM + c0 + sp * 8, At + slot * 8);
    }
#pragma unroll
    for (int i = 0; i < 2; ++i) {
      int slot = i * 256 + tid;
      int r = slot >> 3, s = slot & 7, sp = s ^ (r & 7);
      g2lds16(Bg + (size_t)r * CDIM + c0 + sp * 8, Bt + slot * 8);
    }
    __syncthreads();
#pragma unroll
    for (int kk = 0; kk < 2; ++kk) {
      f16x8 af[2], bf;
#pragma unroll
      for (int nf = 0; nf < 2; ++nf)
        af[nf] = ldsfrag(At, w * 32 + nf * 16 + lr, kk, lh);
#pragma unroll
      for (int kf = 0; kf < 4; ++kf) {
        bf = ldsfrag(Bt, kf * 16 + lr, kk, lh);
#pragma unroll
        for (int nf = 0; nf < 2; ++nf)
          acc[nf][kf] = __builtin_amdgcn_mfma_f32_16x16x32_f16(af[nf], bf,
                                                               acc[nf][kf], 0, 0, 0);
      }
    }
    __syncthreads();
  }
#pragma unroll
  for (int nf = 0; nf < 2; ++nf) {
#pragma unroll
    for (int r = 0; r < 4; ++r) {
      float m = fmaxf(fmaxf(acc[nf][0][r], acc[nf][1][r]),
                      fmaxf(acc[nf][2][r], acc[nf][3][r]));
#pragma unroll
      for (int d = 8; d >= 1; d >>= 1) m = fmaxf(m, __shfl_xor(m, d));
      float e[4], s = 0.f;
#pragma unroll
      for (int kf = 0; kf < 4; ++kf) { e[kf] = __expf(acc[nf][kf][r] - m); s += e[kf]; }
#pragma unroll
      for (int d = 8; d >= 1; d >>= 1) s += __shfl_xor(s, d);
      float inv = 1.f / s;
      int row = w * 32 + nf * 16 + lh * 4 + r;
#pragma unroll
      for (int kf = 0; kf < 4; ++kf)
        zs[row][kf * 16 + lr] = (_Float16)(e[kf] * inv);
    }
  }
  __syncthreads();
  _Float16* zTb = zT + (size_t)b * KDIM * NDIM;
  if (writeZ) {
    _Float16* zb = z + (size_t)b * NDIM * KDIM;
#pragma unroll
    for (int i = 0; i < 4; ++i) {  // z[n][k]
      int idx = i * 256 + tid;
      int n = idx >> 3, ch = idx & 7;
      *reinterpret_cast<uint4*>(&zb[(size_t)(n0 + n) * KDIM + ch * 8]) =
          *reinterpret_cast<const uint4*>(&zs[n][ch * 8]);
    }
  }
#pragma unroll
  for (int i = 0; i < 4; ++i) {  // zT[k][n]
    int idx = i * 256 + tid;
    int k = idx >> 4, nch = idx & 15;
    f16x8 v;
#pragma unroll
    for (int j = 0; j < 8; ++j) v[j] = zs[nch * 8 + j][k];
    *reinterpret_cast<f16x8*>(&zTb[(size_t)k * NDIM + n0 + nch * 8]) = v;
  }
  {  // colsum: thread (q=tid>>6, k=tid&63) sums 32 rows
    int k = tid & 63, q = tid >> 6;
    float s = 0.f;
#pragma unroll
    for (int n = 0; n < 32; ++n) s += (float)zs[q * 32 + n][k];
    csum[q][k] = s;
  }
  __syncthreads();
  if (tid < 64)
    atomicAdd(&colsum[b * KDIM + tid],
              csum[0][tid] + csum[1][tid] + csum[2][tid] + csum[3][tid]);
}

// ---------------------------------------------------------------------------
// S2 (fp16 MFMA): mu_part[s][b][k][c] = sum_{n in split} zT[k][n] xf[c][n]
// grid (C/128, NSPLIT, B). 64k x 128c tile; 16 n-steps of 64.
// ---------------------------------------------------------------------------
__global__ __launch_bounds__(256) void k_s2_16(const _Float16* __restrict__ zT,
                                               const _Float16* __restrict__ xf,
                                               float* __restrict__ mupart) {
  __shared__ __align__(16) short At[64 * 64];
  __shared__ __align__(16) short Bt[128 * 64];
  const int tid = threadIdx.x;
  const int l = tid & 63, w = tid >> 6;
  const int lr = l & 15, lh = l >> 4;
  const int c0 = blockIdx.x * 128;
  const int split = blockIdx.y;
  const int b = blockIdx.z;
  const short* Ag = (const short*)(zT + (size_t)b * KDIM * NDIM);
  const short* Bg = (const short*)(xf + (size_t)b * CDIM * NDIM);
  f32x4 acc[4][2] = {};
  for (int st = 0; st < NDIM / NSPLIT / 64; ++st) {
    const int nb = split * (NDIM / NSPLIT) + st * 64;
#pragma unroll
    for (int i = 0; i < 2; ++i) {
      int slot = i * 256 + tid;
      int r = slot >> 3, s = slot & 7, sp = s ^ (r & 7);
      g2lds16(Ag + (size_t)r * NDIM + nb + sp * 8, At + slot * 8);
    }
#pragma unroll
    for (int i = 0; i < 4; ++i) {
      int slot = i * 256 + tid;
      int r = slot >> 3, s = slot & 7, sp = s ^ (r & 7);
      g2lds16(Bg + (size_t)(c0 + r) * NDIM + nb + sp * 8, Bt + slot * 8);
    }
    __syncthreads();
#pragma unroll
    for (int kk = 0; kk < 2; ++kk) {
      f16x8 bf[2], af;
#pragma unroll
      for (int cf = 0; cf < 2; ++cf)
        bf[cf] = ldsfrag(Bt, w * 32 + cf * 16 + lr, kk, lh);
#pragma unroll
      for (int kf = 0; kf < 4; ++kf) {
        af = ldsfrag(At, kf * 16 + lr, kk, lh);
#pragma unroll
        for (int cf = 0; cf < 2; ++cf)
          acc[kf][cf] = __builtin_amdgcn_mfma_f32_16x16x32_f16(af, bf[cf],
                                                               acc[kf][cf], 0, 0, 0);
      }
    }
    __syncthreads();
  }
  float* mp = mupart + ((size_t)(split * BDIM + b) * KDIM) * CDIM;
#pragma unroll
  for (int kf = 0; kf < 4; ++kf) {
    int k = kf * 16 + lh * 4;
#pragma unroll
    for (int r = 0; r < 4; ++r)
#pragma unroll
      for (int cf = 0; cf < 2; ++cf)
        mp[(size_t)(k + r) * CDIM + c0 + w * 32 + cf * 16 + lr] = acc[kf][cf][r];
  }
}

// ---------------------------------------------------------------------------
// S2 reduce: v[c] = sum_s mu_part; t = v*scs[k]; out = t/(1e-6+|t|_2)
// ---------------------------------------------------------------------------
__global__ __launch_bounds__(256) void k_s2red(const float* __restrict__ mupart,
                                               const float* __restrict__ colsum,
                                               _Float16* __restrict__ muT,
                                               _Float16* __restrict__ mu_ck) {
  __shared__ float red[4];
  const int tid = threadIdx.x;
  const int b = blockIdx.x >> 6, k = blockIdx.x & 63;
  float v0 = 0.f, v1 = 0.f;
#pragma unroll
  for (int s = 0; s < NSPLIT; ++s) {
    const float* mp = mupart + ((size_t)(s * BDIM + b) * KDIM + k) * CDIM;
    v0 += mp[tid];
    v1 += mp[tid + 256];
  }
  float ssq = v0 * v0 + v1 * v1;
#pragma unroll
  for (int d = 32; d >= 1; d >>= 1) ssq += __shfl_down(ssq, d);
  if ((tid & 63) == 0) red[tid >> 6] = ssq;
  __syncthreads();
  float tot = red[0] + red[1] + red[2] + red[3];
  float scs = 1.f / (1e-6f + colsum[b * KDIM + k]);
  float inv = scs / (1e-6f + scs * sqrtf(tot));
  _Float16 o0 = (_Float16)(v0 * inv), o1 = (_Float16)(v1 * inv);
  muT[((size_t)b * KDIM + k) * CDIM + tid] = o0;
  muT[((size_t)b * KDIM + k) * CDIM + tid + 256] = o1;
  mu_ck[((size_t)b * CDIM + tid) * KDIM + k] = o0;
  mu_ck[((size_t)b * CDIM + tid + 256) * KDIM + k] = o1;
}

// ---------------------------------------------------------------------------
// recon (fp16 MFMA): reconT[n][c] = relu(sum_k z[n][k] mu_ck[c][k])
// grid (N/128, C/128, B)
// ---------------------------------------------------------------------------
__global__ __launch_bounds__(256) void k_recon16(const _Float16* __restrict__ z,
                                                 const _Float16* __restrict__ mu_ck,
                                                 _Float16* __restrict__ reconT) {
  __shared__ __align__(16) short Az[128 * 64];
  __shared__ __align__(16) short Bm[128 * 64];
  const int tid = threadIdx.x;
  const int l = tid & 63, w = tid >> 6;
  const int wm = w >> 1, wn = w & 1;
  const int lr = l & 15, lh = l >> 4;
  const int n0 = blockIdx.x * 128;
  const int c0 = blockIdx.y * 128;
  const int b = blockIdx.z;
  const short* Ag = (const short*)(z + (size_t)b * NDIM * KDIM);
  const short* Bg = (const short*)(mu_ck + (size_t)b * CDIM * KDIM);
#pragma unroll
  for (int i = 0; i < 4; ++i) {
    int slot = i * 256 + tid;
    int r = slot >> 3, s = slot & 7, sp = s ^ (r & 7);
    g2lds16(Ag + (size_t)(n0 + r) * KDIM + sp * 8, Az + slot * 8);
  }
#pragma unroll
  for (int i = 0; i < 4; ++i) {
    int slot = i * 256 + tid;
    int r = slot >> 3, s = slot & 7, sp = s ^ (r & 7);
    g2lds16(Bg + (size_t)(c0 + r) * KDIM + sp * 8, Bm + slot * 8);
  }
  __syncthreads();
  f32x4 acc[4][4] = {};
#pragma unroll
  for (int kk = 0; kk < 2; ++kk) {
    f16x8 af[4], bf[4];
#pragma unroll
    for (int m = 0; m < 4; ++m) af[m] = ldsfrag(Az, wm * 64 + m * 16 + lr, kk, lh);
#pragma unroll
    for (int nf = 0; nf < 4; ++nf) bf[nf] = ldsfrag(Bm, wn * 64 + nf * 16 + lr, kk, lh);
#pragma unroll
    for (int m = 0; m < 4; ++m)
#pragma unroll
      for (int nf = 0; nf < 4; ++nf)
        acc[m][nf] = __builtin_amdgcn_mfma_f32_16x16x32_f16(af[m], bf[nf],
                                                            acc[m][nf], 0, 0, 0);
  }
  _Float16* ob = reconT + (size_t)b * NDIM * CDIM;
#pragma unroll
  for (int m = 0; m < 4; ++m) {
#pragma unroll
    for (int r = 0; r < 4; ++r) {
      int n = n0 + wm * 64 + m * 16 + lh * 4 + r;
#pragma unroll
      for (int nf = 0; nf < 4; ++nf) {
        int c = c0 + wn * 64 + nf * 16 + lr;
        ob[(size_t)n * CDIM + c] = (_Float16)fmaxf(acc[m][nf][r], 0.f);
      }
    }
  }
}

// ---------------------------------------------------------------------------
// final: out = relu((y-mean)*rsqrt(var+eps)*gamma + beta + x), y fp16
// ---------------------------------------------------------------------------
__global__ void k_final(float* __restrict__ out, const _Float16* __restrict__ y16,
                        const float* __restrict__ x,
                        const float* __restrict__ bnsum,
                        const float* __restrict__ bnsumsq,
                        const float* __restrict__ gamma,
                        const float* __restrict__ beta) {
  const float invM = 1.f / (BDIM * (float)NDIM);
  const size_t total4 = (size_t)BDIM * CDIM * NDIM / 4;
  for (size_t i4 = (size_t)blockIdx.x * 256 + threadIdx.x; i4 < total4;
       i4 += (size_t)gridDim.x * 256) {
    int c = (int)((i4 >> 10) & (CDIM - 1));
    float mean = bnsum[c] * invM;
    float var = bnsumsq[c] * invM - mean * mean;
    float sc = rsqrtf(var + 1e-5f) * gamma[c];
    float sh = beta[c] - mean * sc;
    f16x4 yv = *reinterpret_cast<const f16x4*>(&y16[i4 * 4]);
    float4 xv = reinterpret_cast<const float4*>(x)[i4];
    float4 o;
    o.x = fmaxf(fmaf((float)yv[0], sc, sh) + xv.x, 0.f);
    o.y = fmaxf(fmaf((float)yv[1], sc, sh) + xv.y, 0.f);
    o.z = fmaxf(fmaf((float)yv[2], sc, sh) + xv.z, 0.f);
    o.w = fmaxf(fmaf((float)yv[3], sc, sh) + xv.w, 0.f);
    reinterpret_cast<float4*>(out)[i4] = o;
  }
}

// ---------------------------------------------------------------------------
extern "C" void kernel_launch(void* const* d_in, const int* in_sizes, int n_in,
                              void* d_out, int out_size, void* d_ws,
                              size_t ws_size, hipStream_t stream) {
  const float* x = (const float*)d_in[0];
  const float* mu = (const float*)d_in[1];
  const float* w1 = (const float*)d_in[2];
  const float* b1 = (const float*)d_in[3];
  const float* w2 = (const float*)d_in[4];
  const float* gamma = (const float*)d_in[5];
  const float* beta = (const float*)d_in[6];
  float* out = (float*)d_out;

  // xf dual copies live in d_out until k_final overwrites it.
  _Float16* xfT = (_Float16*)d_out;              // [B][N][C]
  _Float16* xf = (_Float16*)d_out + 33554432;    // [B][C][N]

  _Float16* wsH = (_Float16*)d_ws;
  _Float16* xT = wsH;                            // [B][N][C] (reused as reconT)
  _Float16* reconT = wsH;
  _Float16* z = wsH + 33554432;                  // [B][N][K]
  _Float16* zT = z + 4194304;                    // [B][K][N]
  _Float16* muT = zT + 4194304;                  // [B][K][C]
  _Float16* mu_ck = muT + 524288;                // [B][C][K]
  _Float16* w1h = mu_ck + 524288;                // [C][C]
  _Float16* w2h = w1h + 262144;
  float* wsF = (float*)(w2h + 262144);
  float* mupart = wsF;                           // [S=4][B][K][C] f32
  float* colsum = mupart + 2097152;              // [B][K]
  float* bnsum = colsum + 1024;                  // [C]
  float* bnsumsq = bnsum + 512;                  // [C]
  _Float16* y16 = (_Float16*)(bnsumsq + 512);    // [B][C][N] fp16

  k_cvtT16<<<dim3(NDIM / 64, CDIM / 64, BDIM), 256, 0, stream>>>(x, xT);
  k_cvt_w16<<<CDIM * CDIM / 1024, 256, 0, stream>>>(w1, w1h);
  k_cvt_w16<<<CDIM * CDIM / 1024, 256, 0, stream>>>(w2, w2h);

  k_conv1_16<<<dim3(NDIM / 128, CDIM / 128, BDIM), 256, 0, stream>>>(
      xT, w1h, b1, xfT, xf);
  k_init_mu16<<<2048, 256, 0, stream>>>(mu, muT);

  for (int s = 0; s < 3; ++s) {
    hipMemsetAsync(colsum, 0, 1024 * sizeof(float), stream);
    k_s1_16<<<dim3(NDIM / 128, BDIM), 256, 0, stream>>>(xfT, muT, z, zT, colsum,
                                                        s == 2 ? 1 : 0);
    k_s2_16<<<dim3(CDIM / 128, NSPLIT, BDIM), 256, 0, stream>>>(zT, xf, mupart);
    k_s2red<<<KDIM * BDIM, 256, 0, stream>>>(mupart, colsum, muT, mu_ck);
  }

  k_recon16<<<dim3(NDIM / 128, CDIM / 128, BDIM), 256, 0, stream>>>(z, mu_ck,
                                                                    reconT);
  hipMemsetAsync(bnsum, 0, 1024 * sizeof(float), stream);
  k_conv2_16<<<dim3(NDIM / 128, CDIM / 128, BDIM), 256, 0, stream>>>(
      w2h, reconT, y16, bnsum, bnsumsq);

  k_final<<<4096, 256, 0, stream>>>(out, y16, x, bnsum, bnsumsq, gamma, beta);
}